// Round 17
// baseline (239.629 us; speedup 1.0000x reference)
//
#include <hip/hip_runtime.h>
#include <stdint.h>

#define B 64
#define H 384
#define W 512
#define NPX (H*W)            // 196608
#define TRIM_IDX 157286      // int(0.8 * 196608)
#define RPW 8                // rows per wave in loss kernel

#define NBA 2048
#define CAPW 64              // per-wave candidate cap
#define NSLOT 256            // waves per sample in collect
#define CAPD 12288           // dense LDS candidate cap in small3 (48 KB)
#define SCAP 6144            // sample stash cap
#define DELTA 0.03f          // sample-quantile half-window

// ---- workspace layout (uint32 units) ----
#define N_OFF    0           // [B]  u32 mask count
#define MS_OFF   64          // [3][B] u32 subsample mask counts
#define TS_OFF   256         // [B]  f32 tmae sum
#define GS_OFF   320         // [4][B] f32 grad sums
#define TSUM_OFF 576         // [2][B] f32 total masked value sum
#define SB_OFF   704         // [2][B] f32 sum below (bracket, then median)
#define CB_OFF   832         // [2][B] u32 count below bracket
#define OVF_OFF  960         // [2][B] u32 overflow flag
#define ZERO_U32 1088
// persistent (written before read each launch)
#define BL_OFF   1088        // [2][B] u32 bracket lo (20-bit prefix)
#define BH_OFF   1216        // [2][B] u32 bracket hi
#define K_OFF    1344        // [2][B] u32 k3 (rank within final value)
#define EQ_OFF   1472        // [2][B] u32 count equal to median
#define SH_OFF   1600        // [2][B] f32 median (shift)
#define RS_OFF   1728        // [2][B] f32 reciprocal scale
#define THR_OFF  1856        // [B]  f32 trim threshold
#define C2_OFF   1920        // [B]  u32 count targ>shift_t
#define CNTW_OFF 1984        // [2][B][NSLOT] u32 per-wave counts
#define FIX_U32  (1984 + 2*B*NSLOT)
#define BUF_OFF  FIX_U32     // [2][B][NSLOT][capw] f32 candidates

__device__ __forceinline__ uint32_t fmap(float f) {
    uint32_t b = __float_as_uint(f);
    return (b & 0x80000000u) ? ~b : (b | 0x80000000u);
}
__device__ __forceinline__ float funmap(uint32_t u) {
    uint32_t b = (u & 0x80000000u) ? (u & 0x7fffffffu) : ~u;
    return __uint_as_float(b);
}

// ---------------- sample: per-sample 20-bit median bracket from 8192 elems ----------------
__global__ void __launch_bounds__(1024) sample_kernel(const float* __restrict__ pred,
                                                      const float* __restrict__ targ,
                                                      uint32_t* __restrict__ ws) {
    __shared__ uint32_t kp[SCAP], kt[SCAP];
    __shared__ uint32_t h[4096];
    __shared__ uint32_t sc[256];
    __shared__ uint32_t s_ct, s_lo12, s_hi12, s_clo, s_bl, s_bh;
    const int b = blockIdx.x;
    const int t = threadIdx.x;
    const int lane = t & 63;
    if (t == 0) s_ct = 0;
    __syncthreads();
    const float4* pb = (const float4*)(pred + (size_t)b * NPX);
    const float4* tb = (const float4*)(targ + (size_t)b * NPX);
    #pragma unroll
    for (int c = 0; c < 2; c++) {
        int j = t + c * 1024;
        int q = ((j >> 6) * 1536) + (j & 63);
        float4 tv = tb[q], pv = pb[q];
        float tA[4] = {tv.x, tv.y, tv.z, tv.w};
        float pA[4] = {pv.x, pv.y, pv.z, pv.w};
        #pragma unroll
        for (int e = 0; e < 4; e++) {
            bool msk = tA[e] > 0.f;
            unsigned long long bal = __ballot(msk);
            if (bal) {
                int leader = __ffsll((long long)bal) - 1;
                uint32_t base = 0;
                if (lane == leader) base = atomicAdd(&s_ct, (uint32_t)__popcll(bal));
                base = (uint32_t)__shfl((int)base, leader, 64);
                if (msk) {
                    uint32_t off = base + (uint32_t)__popcll(bal & ((1ull << lane) - 1ull));
                    if (off < SCAP) { kt[off] = fmap(tA[e]); kp[off] = fmap(pA[e]); }
                }
            }
        }
    }
    __syncthreads();
    const uint32_t ct = s_ct;
    const bool ok = (ct > 0) && (ct <= SCAP);
    for (int w = 0; w < 2; w++) {
        const uint32_t* K = (w == 0) ? kp : kt;
        uint32_t BL = 0, BH = 0xFFFFFu;
        if (ok) {
            uint32_t rlo = (uint32_t)((0.5f - DELTA) * (float)ct);
            uint32_t rhi = (uint32_t)((0.5f + DELTA) * (float)ct);
            if (rhi >= ct) rhi = ct - 1;
            for (int i = t; i < 4096; i += 1024) h[i] = 0;
            __syncthreads();
            for (uint32_t j = t; j < ct; j += 1024) atomicAdd(&h[K[j] >> 20], 1u);
            __syncthreads();
            uint32_t ms = 0;
            if (t < 256) { for (int i = 0; i < 16; i++) ms += h[t * 16 + i]; sc[t] = ms; }
            __syncthreads();
            for (int off = 1; off < 256; off <<= 1) {
                uint32_t a = (t < 256 && t >= off) ? sc[t - off] : 0u;
                __syncthreads();
                if (t < 256) sc[t] += a;
                __syncthreads();
            }
            if (t < 256) {
                uint32_t incl = sc[t], excl = incl - ms;
                if (rlo >= excl && rlo < incl) {
                    uint32_t c2 = excl;
                    for (int i = 0; i < 16; i++) {
                        uint32_t hv = h[t * 16 + i];
                        if (rlo < c2 + hv) { s_lo12 = t * 16 + i; s_clo = c2; break; }
                        c2 += hv;
                    }
                }
                if (rhi >= excl && rhi < incl) {
                    uint32_t c2 = excl;
                    for (int i = 0; i < 16; i++) {
                        uint32_t hv = h[t * 16 + i];
                        if (rhi < c2 + hv) { s_hi12 = t * 16 + i; break; }
                        c2 += hv;
                    }
                }
            }
            __syncthreads();
            const uint32_t lo12 = s_lo12, hi12 = s_hi12, clo = s_clo;
            const uint32_t range = (hi12 - lo12 + 1) << 8;
            if (range > 4096) {
                BL = lo12 << 8; BH = (hi12 << 8) | 255u;
            } else {
                for (int i = t; i < 4096; i += 1024) h[i] = 0;
                __syncthreads();
                const uint32_t base20 = lo12 << 8;
                for (uint32_t j = t; j < ct; j += 1024) {
                    uint32_t u = K[j], u12 = u >> 20;
                    if (u12 >= lo12 && u12 <= hi12) atomicAdd(&h[(u >> 12) - base20], 1u);
                }
                __syncthreads();
                const uint32_t r2lo = rlo - clo, r2hi = rhi - clo;
                uint32_t ms2 = 0;
                if (t < 256) { for (int i = 0; i < 16; i++) ms2 += h[t * 16 + i]; sc[t] = ms2; }
                __syncthreads();
                for (int off = 1; off < 256; off <<= 1) {
                    uint32_t a = (t < 256 && t >= off) ? sc[t - off] : 0u;
                    __syncthreads();
                    if (t < 256) sc[t] += a;
                    __syncthreads();
                }
                if (t < 256) {
                    uint32_t incl = sc[t], excl = incl - ms2;
                    if (r2lo >= excl && r2lo < incl) {
                        uint32_t c2 = excl;
                        for (int i = 0; i < 16; i++) {
                            uint32_t hv = h[t * 16 + i];
                            if (r2lo < c2 + hv) { s_bl = base20 + t * 16 + i; break; }
                            c2 += hv;
                        }
                    }
                    if (r2hi >= excl && r2hi < incl) {
                        uint32_t c2 = excl;
                        for (int i = 0; i < 16; i++) {
                            uint32_t hv = h[t * 16 + i];
                            if (r2hi < c2 + hv) { s_bh = base20 + t * 16 + i; break; }
                            c2 += hv;
                        }
                    }
                }
                __syncthreads();
                BL = s_bl; BH = s_bh;
            }
        }
        if (t == 0) { ws[BL_OFF + w * B + b] = BL; ws[BH_OFF + w * B + b] = BH; }
        __syncthreads();
    }
}

// ---------------- single full pass: n/sums + below-bracket count/sum + compaction ----------------
// grid (64,B) x 256: 12 elems/thread, single round, all 6 loads hoisted, one wave scan
__global__ void __launch_bounds__(256) collect_kernel(const float* __restrict__ pred,
                                                      const float* __restrict__ targ,
                                                      uint32_t* __restrict__ ws, int capw) {
    const int b = blockIdx.y;
    const int t = threadIdx.x;
    const int lane = t & 63;
    const int slot = (blockIdx.x << 2) + (t >> 6);    // [0,256)
    const uint32_t BLp = ws[BL_OFF + b],     BHp = ws[BH_OFF + b];
    const uint32_t BLt = ws[BL_OFF + B + b], BHt = ws[BH_OFF + B + b];
    const float4* pb = (const float4*)(pred + (size_t)b * NPX);
    const float4* tb = (const float4*)(targ + (size_t)b * NPX);
    const int tid = blockIdx.x * 256 + t;             // [0,16384)
    float* bufp = ((float*)(ws + BUF_OFF)) + ((size_t)b * NSLOT + slot) * capw;
    float* buft = ((float*)(ws + BUF_OFF)) + (((size_t)B + b) * NSLOT + slot) * capw;

    float4 ta0 = tb[tid], ta1 = tb[tid + 16384], ta2 = tb[tid + 32768];
    float4 pa0 = pb[tid], pa1 = pb[tid + 16384], pa2 = pb[tid + 32768];
    float tA[12] = {ta0.x,ta0.y,ta0.z,ta0.w, ta1.x,ta1.y,ta1.z,ta1.w, ta2.x,ta2.y,ta2.z,ta2.w};
    float pA[12] = {pa0.x,pa0.y,pa0.z,pa0.w, pa1.x,pa1.y,pa1.z,pa1.w, pa2.x,pa2.y,pa2.z,pa2.w};

    float sbp = 0.f, sbt = 0.f, sump = 0.f, sumt = 0.f;
    uint32_t nloc = 0, cbp = 0, cbt = 0;
    uint32_t mbp = 0, mbt = 0;
    #pragma unroll
    for (int e = 0; e < 12; e++) {
        float tv = tA[e], pv = pA[e];
        if (tv > 0.f) {
            nloc++; sumt += tv; sump += pv;
            uint32_t up = fmap(pv) >> 12, ut = fmap(tv) >> 12;
            if (up < BLp) { cbp++; sbp += pv; }
            else if (up <= BHp) mbp |= (1u << e);
            if (ut < BLt) { cbt++; sbt += tv; }
            else if (ut <= BHt) mbt |= (1u << e);
        }
    }
    uint32_t packed = (uint32_t)__popc(mbp) | ((uint32_t)__popc(mbt) << 16);
    uint32_t scan = packed;
    #pragma unroll
    for (int off = 1; off < 64; off <<= 1) {
        uint32_t v = (uint32_t)__shfl_up((int)scan, off, 64);
        if (lane >= off) scan += v;
    }
    uint32_t tot = (uint32_t)__shfl((int)scan, 63, 64);
    uint32_t exl = scan - packed;
    uint32_t op = exl & 0xFFFFu;
    uint32_t ot = exl >> 16;
    if (mbp | mbt) {
        #pragma unroll
        for (int e = 0; e < 12; e++) {
            if ((mbp >> e) & 1u) { if (op < (uint32_t)capw) bufp[op] = pA[e]; op++; }
            if ((mbt >> e) & 1u) { if (ot < (uint32_t)capw) buft[ot] = tA[e]; ot++; }
        }
    }
    if (lane == 0) {
        uint32_t wp = tot & 0xFFFFu, wt = tot >> 16;
        ws[CNTW_OFF + b * NSLOT + slot] = wp;
        ws[CNTW_OFF + (B + b) * NSLOT + slot] = wt;
        if (wp > (uint32_t)capw) ws[OVF_OFF + b] = 1u;
        if (wt > (uint32_t)capw) ws[OVF_OFF + B + b] = 1u;
    }
    for (int off = 32; off; off >>= 1) {
        nloc += __shfl_down(nloc, off, 64);
        sump += __shfl_down(sump, off, 64);
        sumt += __shfl_down(sumt, off, 64);
        sbp  += __shfl_down(sbp, off, 64);
        sbt  += __shfl_down(sbt, off, 64);
        cbp  += __shfl_down(cbp, off, 64);
        cbt  += __shfl_down(cbt, off, 64);
    }
    if (lane == 0) {
        if (nloc) atomicAdd(ws + N_OFF + b, nloc);
        atomicAdd(((float*)(ws + TSUM_OFF)) + b, sump);
        atomicAdd(((float*)(ws + TSUM_OFF)) + B + b, sumt);
        atomicAdd(((float*)(ws + SB_OFF)) + b, sbp);
        atomicAdd(((float*)(ws + SB_OFF)) + B + b, sbt);
        if (cbp) atomicAdd(ws + CB_OFF + b, cbp);
        if (cbt) atomicAdd(ws + CB_OFF + B + b, cbt);
    }
}

// ---------------- small select: dense gather -> 3-stage (12+11+9) LDS radix ----------------
__global__ void small3_kernel(const float* __restrict__ pred,
                              const float* __restrict__ targ,
                              uint32_t* __restrict__ ws, int capw) {
    const int b = blockIdx.x, which = blockIdx.y;
    const int t = threadIdx.x;
    __shared__ float dense[CAPD];        // 48 KB
    __shared__ uint32_t cnt[4096];       // 16 KB
    __shared__ float fsm[4096];          // 16 KB
    __shared__ uint32_t sc[256];
    __shared__ float sfl[256];
    __shared__ uint32_t scnt[NSLOT], soff[NSLOT];
    __shared__ uint32_t r_bin, r_k, s_Ctot;
    __shared__ float r_f, s_facc;
    const uint32_t n = ws[N_OFF + b];
    const uint32_t k0 = (n - 1u) >> 1;
    const uint32_t CBv = ws[CB_OFF + which * B + b];
    const uint32_t* cw = ws + CNTW_OFF + (which * B + b) * NSLOT;
    const float* bufb = ((const float*)(ws + BUF_OFF)) + ((size_t)which * B + b) * NSLOT * capw;
    const float* Tp = targ + (size_t)b * NPX;
    const float* Pp = pred + (size_t)b * NPX;

    // ---- gather counts -> prefix -> dense LDS copy ----
    uint32_t myc = (t < NSLOT) ? cw[t] : 0u;
    sc[t] = myc;
    __syncthreads();
    for (int off = 1; off < NSLOT; off <<= 1) {
        uint32_t a = (t >= off) ? sc[t - off] : 0u;
        __syncthreads();
        sc[t] += a;
        __syncthreads();
    }
    if (t < NSLOT) { scnt[t] = myc; soff[t] = sc[t] - myc; }
    if (t == NSLOT - 1) s_Ctot = sc[t];
    __syncthreads();
    const uint32_t Ctot = s_Ctot;
    const long k_in = (long)k0 - (long)CBv;
    const bool fast = (capw > 0) && (ws[OVF_OFF + which * B + b] == 0u) &&
                      (Ctot <= (uint32_t)CAPD) && (k_in >= 0) && (k_in < (long)Ctot);
    if (fast) {
        const float* sb_ = bufb + (size_t)t * capw;   // 1 thread per slot
        const uint32_t nn = scnt[t], o = soff[t];
        for (uint32_t j = 0; j < nn; j++) dense[o + j] = sb_[j];
    }
    __syncthreads();

    uint32_t kr = fast ? (uint32_t)k_in : k0;

    // ---- stage 0: top 12 bits ----
    for (int i = t; i < 4096; i += 256) { cnt[i] = 0; fsm[i] = 0.f; }
    __syncthreads();
    if (fast) {
        for (uint32_t j = t; j < Ctot; j += 256) {
            float v = dense[j];
            uint32_t key = fmap(v) >> 20;
            atomicAdd(&cnt[key], 1u); atomicAdd(&fsm[key], v);
        }
    } else {
        for (int j = t; j < NPX; j += 256) {
            float tvv = Tp[j];
            if (tvv > 0.f) {
                float v = (which == 0) ? Pp[j] : tvv;
                uint32_t key = fmap(v) >> 20;
                atomicAdd(&cnt[key], 1u); atomicAdd(&fsm[key], v);
            }
        }
    }
    __syncthreads();
    {
        uint32_t ms = 0; float mf = 0.f;
        #pragma unroll
        for (int i = 0; i < 16; i++) { ms += cnt[t * 16 + i]; mf += fsm[t * 16 + i]; }
        sc[t] = ms; sfl[t] = mf;
        __syncthreads();
        for (int off = 1; off < 256; off <<= 1) {
            uint32_t a = (t >= off) ? sc[t - off] : 0u;
            float af = (t >= off) ? sfl[t - off] : 0.f;
            __syncthreads();
            sc[t] += a; sfl[t] += af;
            __syncthreads();
        }
        uint32_t incl = sc[t], excl = incl - ms;
        float fx = sfl[t] - mf;
        if (kr >= excl && kr < incl) {
            uint32_t c = excl, bin = 0, nk = 0; float f = fx;
            for (int i = 0; i < 16; i++) {
                uint32_t hv = cnt[t * 16 + i];
                if (kr < c + hv) { bin = t * 16 + i; nk = kr - c; break; }
                c += hv; f += fsm[t * 16 + i];
            }
            r_bin = bin; r_k = nk; r_f = f;
        }
    }
    __syncthreads();
    const uint32_t sel0 = r_bin;
    kr = r_k;
    if (t == 0) s_facc = r_f;
    __syncthreads();

    // ---- stage 1: mid 11 bits within sel0 ----
    for (int i = t; i < NBA; i += 256) { cnt[i] = 0; fsm[i] = 0.f; }
    __syncthreads();
    if (fast) {
        for (uint32_t j = t; j < Ctot; j += 256) {
            float v = dense[j];
            uint32_t u = fmap(v);
            if ((u >> 20) == sel0) {
                uint32_t key = (u >> 9) & (NBA - 1u);
                atomicAdd(&cnt[key], 1u); atomicAdd(&fsm[key], v);
            }
        }
    } else {
        for (int j = t; j < NPX; j += 256) {
            float tvv = Tp[j];
            if (tvv > 0.f) {
                float v = (which == 0) ? Pp[j] : tvv;
                uint32_t u = fmap(v);
                if ((u >> 20) == sel0) {
                    uint32_t key = (u >> 9) & (NBA - 1u);
                    atomicAdd(&cnt[key], 1u); atomicAdd(&fsm[key], v);
                }
            }
        }
    }
    __syncthreads();
    {
        uint32_t ms = 0; float mf = 0.f;
        #pragma unroll
        for (int i = 0; i < 8; i++) { ms += cnt[t * 8 + i]; mf += fsm[t * 8 + i]; }
        sc[t] = ms; sfl[t] = mf;
        __syncthreads();
        for (int off = 1; off < 256; off <<= 1) {
            uint32_t a = (t >= off) ? sc[t - off] : 0u;
            float af = (t >= off) ? sfl[t - off] : 0.f;
            __syncthreads();
            sc[t] += a; sfl[t] += af;
            __syncthreads();
        }
        uint32_t incl = sc[t], excl = incl - ms;
        float fx = sfl[t] - mf;
        if (kr >= excl && kr < incl) {
            uint32_t c = excl, bin = 0, nk = 0; float f = fx;
            for (int i = 0; i < 8; i++) {
                uint32_t hv = cnt[t * 8 + i];
                if (kr < c + hv) { bin = t * 8 + i; nk = kr - c; break; }
                c += hv; f += fsm[t * 8 + i];
            }
            r_bin = bin; r_k = nk; r_f = f;
        }
    }
    __syncthreads();
    const uint32_t pfx23 = (sel0 << 11) | r_bin;
    kr = r_k;
    if (t == 0) s_facc += r_f;
    __syncthreads();

    // ---- stage 2: low 9 bits ----
    for (int i = t; i < 512; i += 256) { cnt[i] = 0; fsm[i] = 0.f; }
    __syncthreads();
    if (fast) {
        for (uint32_t j = t; j < Ctot; j += 256) {
            float v = dense[j];
            uint32_t u = fmap(v);
            if ((u >> 9) == pfx23) {
                uint32_t key = u & 511u;
                atomicAdd(&cnt[key], 1u); atomicAdd(&fsm[key], v);
            }
        }
    } else {
        for (int j = t; j < NPX; j += 256) {
            float tvv = Tp[j];
            if (tvv > 0.f) {
                float v = (which == 0) ? Pp[j] : tvv;
                uint32_t u = fmap(v);
                if ((u >> 9) == pfx23) {
                    uint32_t key = u & 511u;
                    atomicAdd(&cnt[key], 1u); atomicAdd(&fsm[key], v);
                }
            }
        }
    }
    __syncthreads();
    {
        uint32_t ms = 0; float mf = 0.f;
        #pragma unroll
        for (int i = 0; i < 2; i++) { ms += cnt[t * 2 + i]; mf += fsm[t * 2 + i]; }
        sc[t] = ms; sfl[t] = mf;
        __syncthreads();
        for (int off = 1; off < 256; off <<= 1) {
            uint32_t a = (t >= off) ? sc[t - off] : 0u;
            float af = (t >= off) ? sfl[t - off] : 0.f;
            __syncthreads();
            sc[t] += a; sfl[t] += af;
            __syncthreads();
        }
        uint32_t incl = sc[t], excl = incl - ms;
        float fx = sfl[t] - mf;
        if (kr >= excl && kr < incl) {
            uint32_t c = excl, bin = 0, nk = 0, e = 0; float f = fx;
            for (int i = 0; i < 2; i++) {
                uint32_t hv = cnt[t * 2 + i];
                if (kr < c + hv) { bin = t * 2 + i; nk = kr - c; e = hv; break; }
                c += hv; f += fsm[t * 2 + i];
            }
            uint32_t u = (pfx23 << 9) | bin;
            ((float*)(ws + SH_OFF))[which * B + b] = funmap(u);
            ws[K_OFF + which * B + b] = nk;      // k3
            ws[EQ_OFF + which * B + b] = e;
            float* sb = ((float*)(ws + SB_OFF)) + which * B + b;
            float below = s_facc + f;
            *sb = fast ? (*sb + below) : below;
        }
    }
}

// ---------------- params ----------------
__global__ void param_kernel(const float* __restrict__ pred,
                             const float* __restrict__ targ,
                             uint32_t* __restrict__ ws) {
    const int b = threadIdx.x;
    if (b >= B) return;
    const uint32_t n = ws[N_OFF + b];
    const uint32_t k0 = (n - 1u) >> 1;
    float med[2], rs[2];
    uint32_t nab[2];
    #pragma unroll
    for (int w = 0; w < 2; w++) {
        float m = ((const float*)(ws + SH_OFF))[w * B + b];
        uint32_t k3 = ws[K_OFF + w * B + b];
        uint32_t e = ws[EQ_OFF + w * B + b];
        float SBv = ((const float*)(ws + SB_OFF))[w * B + b];
        float ST = ((const float*)(ws + TSUM_OFF))[w * B + b];
        uint32_t CB = k0 - k3;
        uint32_t na = n - CB - e;
        float Sab = ST - SBv - (float)e * m;
        float absdev = (Sab - (float)na * m) + ((float)CB * m - SBv);
        float scale = absdev / (float)n;
        med[w] = m; nab[w] = na;
        rs[w] = 1.f / scale;
        ((float*)(ws + RS_OFF))[w * B + b] = rs[w];
    }
    uint32_t c2 = nab[1];
    ws[C2_OFF + b] = c2;
    uint32_t mi = (uint32_t)NPX - c2 + (uint32_t)TRIM_IDX;
    if (mi > (uint32_t)(NPX - 1)) mi = NPX - 1;
    float p = pred[(size_t)b * NPX + mi];
    float t = targ[(size_t)b * NPX + mi];
    float pn = (p - med[0]) * rs[0], tn = (t - med[1]) * rs[1];
    ((float*)(ws + THR_OFF))[b] = (tn > 0.f) ? fabsf(pn - tn) : 0.f;
}

// ---------------- fused loss: 8-row strip per wave, 2-deep register ring ----------------
__global__ void __launch_bounds__(256) loss_kernel(const float* __restrict__ pred,
                                                   const float* __restrict__ targ,
                                                   uint32_t* __restrict__ ws) {
    const int wid = (blockIdx.x << 2) + (threadIdx.x >> 6);
    const int b = wid / (H / RPW);
    const int s0 = (wid - b * (H / RPW)) * RPW;
    const int l = threadIdx.x & 63;
    const int col = l << 3;
    const float sp = ((const float*)(ws + SH_OFF))[b];
    const float st = ((const float*)(ws + SH_OFF))[B + b];
    const float rp = ((const float*)(ws + RS_OFF))[b];
    const float rt = ((const float*)(ws + RS_OFF))[B + b];
    const float thr = ((const float*)(ws + THR_OFF))[b];
    const float* Pp = pred + (size_t)b * NPX;
    const float* Tp = targ + (size_t)b * NPX;

    const bool g1 = s0 >= 1, g2 = s0 >= 2, g4 = s0 >= 4, g8 = s0 >= 8;
    float rT[2][8], rPN[2][8];
    {
        const int roA = (g1 ? (s0 - 1) : s0) * W + col;
        const int roB = (g2 ? (s0 - 2) : s0) * W + col;
        float4 a0 = *(const float4*)(Tp + roA), a1 = *(const float4*)(Tp + roA + 4);
        float4 b0 = *(const float4*)(Pp + roA), b1 = *(const float4*)(Pp + roA + 4);
        float4 c0 = *(const float4*)(Tp + roB), c1 = *(const float4*)(Tp + roB + 4);
        float4 d0 = *(const float4*)(Pp + roB), d1 = *(const float4*)(Pp + roB + 4);
        float ta[8] = {a0.x,a0.y,a0.z,a0.w,a1.x,a1.y,a1.z,a1.w};
        float pa[8] = {b0.x,b0.y,b0.z,b0.w,b1.x,b1.y,b1.z,b1.w};
        float tc[8] = {c0.x,c0.y,c0.z,c0.w,c1.x,c1.y,c1.z,c1.w};
        float pc[8] = {d0.x,d0.y,d0.z,d0.w,d1.x,d1.y,d1.z,d1.w};
        #pragma unroll
        for (int k = 0; k < 8; k++) {
            rT[1][k] = ta[k]; rPN[1][k] = (pa[k] - sp) * rp;
            rT[0][k] = tc[k]; rPN[0][k] = (pc[k] - sp) * rp;
        }
    }

    float tl = 0.f, gl0 = 0.f, gl1 = 0.f, gl2 = 0.f, gl3 = 0.f;
    uint32_t mc = 0;

    #pragma unroll
    for (int it = 0; it < RPW; ++it) {
        const int ro = (s0 + it) * W + col;
        const int cur = it & 1, prv = cur ^ 1;
        float4 a0 = *(const float4*)(Tp + ro), a1 = *(const float4*)(Tp + ro + 4);
        float4 b0 = *(const float4*)(Pp + ro), b1 = *(const float4*)(Pp + ro + 4);
        float t[8] = {a0.x,a0.y,a0.z,a0.w,a1.x,a1.y,a1.z,a1.w};
        float p[8] = {b0.x,b0.y,b0.z,b0.w,b1.x,b1.y,b1.z,b1.w};
        float t4a = 0.f, t4b = 0.f, p4a = 0.f, p4b = 0.f, t8a = 0.f, p8a = 0.f;
        if (it == 0) {
            const int ro4 = g4 ? ro - 4 * W : ro;
            t4a = Tp[ro4]; t4b = Tp[ro4 + 4]; p4a = Pp[ro4]; p4b = Pp[ro4 + 4];
            const int ro8 = g8 ? ro - 8 * W : ro;
            t8a = Tp[ro8]; p8a = Pp[ro8];
        }
        if (it == 4) {
            const int ro4 = ro - 4 * W;
            t4a = Tp[ro4]; t4b = Tp[ro4 + 4]; p4a = Pp[ro4]; p4b = Pp[ro4 + 4];
        }
        float pn[8]; bool m[8];
        #pragma unroll
        for (int k = 0; k < 8; k++) { pn[k] = (p[k] - sp) * rp; m[k] = t[k] > st; }

        #pragma unroll
        for (int k = 0; k < 8; k++) {
            if (m[k]) {
                float tn = (t[k] - st) * rt;
                float r = fabsf(pn[k] - tn);
                if (r <= thr) tl += r;
            }
        }
        float t7p = __shfl_up(t[7], 1), pn7p = __shfl_up(pn[7], 1);
        if (l > 0 && m[0] && t7p > st) gl0 += fabsf(pn[0] - pn7p);
        #pragma unroll
        for (int k = 1; k < 8; k++) if (m[k] && m[k - 1]) gl0 += fabsf(pn[k] - pn[k - 1]);
        if (it > 0 || g1) {
            #pragma unroll
            for (int k = 0; k < 8; k++)
                if (m[k] && rT[prv][k] > st) gl0 += fabsf(pn[k] - rPN[prv][k]);
        }
        if ((it & 1) == 0) {
            float t6p = __shfl_up(t[6], 1), pn6p = __shfl_up(pn[6], 1);
            mc += (uint32_t)m[0] + m[2] + m[4] + m[6];
            if (l > 0 && m[0] && t6p > st) gl1 += fabsf(pn[0] - pn6p);
            if (m[2] && m[0]) gl1 += fabsf(pn[2] - pn[0]);
            if (m[4] && m[2]) gl1 += fabsf(pn[4] - pn[2]);
            if (m[6] && m[4]) gl1 += fabsf(pn[6] - pn[4]);
            if (it >= 2 || g2) {
                if (m[0] && rT[cur][0] > st) gl1 += fabsf(pn[0] - rPN[cur][0]);
                if (m[2] && rT[cur][2] > st) gl1 += fabsf(pn[2] - rPN[cur][2]);
                if (m[4] && rT[cur][4] > st) gl1 += fabsf(pn[4] - rPN[cur][4]);
                if (m[6] && rT[cur][6] > st) gl1 += fabsf(pn[6] - rPN[cur][6]);
            }
            if ((it & 3) == 0) {
                float t4p = __shfl_up(t[4], 1), pn4p = __shfl_up(pn[4], 1);
                mc += ((uint32_t)m[0] + m[4]) << 11;
                if (l > 0 && m[0] && t4p > st) gl2 += fabsf(pn[0] - pn4p);
                if (m[4] && m[0]) gl2 += fabsf(pn[4] - pn[0]);
                if (it == 4 || g4) {
                    if (m[0] && t4a > st) gl2 += fabsf(pn[0] - (p4a - sp) * rp);
                    if (m[4] && t4b > st) gl2 += fabsf(pn[4] - (p4b - sp) * rp);
                }
                if (it == 0) {
                    float t0p = __shfl_up(t[0], 1), pn0p = __shfl_up(pn[0], 1);
                    mc += ((uint32_t)m[0]) << 22;
                    if (l > 0 && m[0] && t0p > st) gl3 += fabsf(pn[0] - pn0p);
                    if (g8 && m[0] && t8a > st) gl3 += fabsf(pn[0] - (p8a - sp) * rp);
                }
            }
        }
        #pragma unroll
        for (int k = 0; k < 8; k++) { rT[cur][k] = t[k]; rPN[cur][k] = pn[k]; }
    }

    for (int off = 32; off; off >>= 1) {
        tl  += __shfl_down(tl, off, 64);
        gl0 += __shfl_down(gl0, off, 64);
        gl1 += __shfl_down(gl1, off, 64);
        gl2 += __shfl_down(gl2, off, 64);
        gl3 += __shfl_down(gl3, off, 64);
        mc  += __shfl_down(mc, off, 64);
    }
    if (l == 0) {
        float* gs = (float*)(ws + GS_OFF);
        atomicAdd(((float*)(ws + TS_OFF)) + b, tl);
        atomicAdd(gs + b, gl0);
        atomicAdd(gs + B + b, gl1);
        atomicAdd(gs + 2 * B + b, gl2);
        atomicAdd(gs + 3 * B + b, gl3);
        atomicAdd(ws + MS_OFF + b, mc & 0x7FFu);
        atomicAdd(ws + MS_OFF + B + b, (mc >> 11) & 0x7FFu);
        atomicAdd(ws + MS_OFF + 2 * B + b, mc >> 22);
    }
}

// ---------------- finalize ----------------
__global__ void finalize_kernel(const uint32_t* __restrict__ ws, float* __restrict__ out) {
    const int b = threadIdx.x;
    float v = 0.f;
    if (b < B) {
        float c2 = (float)ws[C2_OFF + b];
        const float* tsum = (const float*)(ws + TS_OFF);
        const float* gsum = (const float*)(ws + GS_OFF);
        float tm = (c2 > 0.f) ? tsum[b] / (2.f * c2) : 0.f;
        float g = (c2 > 0.f) ? gsum[b] / c2 : 0.f;
        for (int z = 0; z < 3; z++) {
            float ms = (float)ws[MS_OFF + z * B + b];
            g += (ms > 0.f) ? gsum[(1 + z) * B + b] / ms : 0.f;
        }
        v = tm + 0.5f * g;
    }
    for (int off = 32; off; off >>= 1) v += __shfl_down(v, off, 64);
    if (b == 0) out[0] = v * (1.f / 64.f);
}

extern "C" void kernel_launch(void* const* d_in, const int* in_sizes, int n_in,
                              void* d_out, int out_size, void* d_ws, size_t ws_size,
                              hipStream_t stream) {
    const float* pred = (const float*)d_in[0];
    const float* targ = (const float*)d_in[1];
    float* out = (float*)d_out;
    uint32_t* ws = (uint32_t*)d_ws;

    long avail = (long)(ws_size / 4) - (long)FIX_U32;
    int capw = 0;
    if (avail > 0) {
        long c = avail / (2L * B * NSLOT);
        capw = (int)(c < CAPW ? c : CAPW);
    }

    hipMemsetAsync(ws, 0, (size_t)ZERO_U32 * 4, stream);

    sample_kernel<<<dim3(B), 1024, 0, stream>>>(pred, targ, ws);
    collect_kernel<<<dim3(64, B), 256, 0, stream>>>(pred, targ, ws, capw);
    small3_kernel<<<dim3(B, 2), 256, 0, stream>>>(pred, targ, ws, capw);
    param_kernel<<<1, 64, 0, stream>>>(pred, targ, ws);
    loss_kernel<<<dim3(B * (H / RPW) / 4), 256, 0, stream>>>(pred, targ, ws);
    finalize_kernel<<<1, 64, 0, stream>>>(ws, out);
}

// Round 18
// 146.999 us; speedup vs baseline: 1.6301x; 1.6301x over previous
//
#include <hip/hip_runtime.h>
#include <stdint.h>

#define B 64
#define H 384
#define W 512
#define NPX (H*W)            // 196608
#define TRIM_IDX 157286      // int(0.8 * 196608)
#define RPW 8                // rows per wave in loss kernel

#define NBA 2048
#define CAPW 256             // per-wave candidate cap
#define NSLOT 64             // waves per sample in collect
#define CAPD 12288           // dense LDS candidate cap in small3 (48 KB)
#define SCAP 6144            // sample stash cap
#define DELTA 0.03f          // sample-quantile half-window

// ---- workspace layout (uint32 units) ----
#define N_OFF    0           // [B]  u32 mask count
#define MS_OFF   64          // [3][B] u32 subsample mask counts
#define TS_OFF   256         // [B]  f32 tmae sum
#define GS_OFF   320         // [4][B] f32 grad sums
#define TSUM_OFF 576         // [2][B] f32 total masked value sum
#define SB_OFF   704         // [2][B] f32 sum below (bracket, then median)
#define CB_OFF   832         // [2][B] u32 count below bracket
#define OVF_OFF  960         // [2][B] u32 overflow flag
#define ZERO_U32 1088
// persistent (written before read each launch)
#define BL_OFF   1088        // [2][B] u32 bracket lo (20-bit prefix)
#define BH_OFF   1216        // [2][B] u32 bracket hi
#define K_OFF    1344        // [2][B] u32 k3 (rank within final value)
#define EQ_OFF   1472        // [2][B] u32 count equal to median
#define SH_OFF   1600        // [2][B] f32 median (shift)
#define RS_OFF   1728        // [2][B] f32 reciprocal scale
#define THR_OFF  1856        // [B]  f32 trim threshold
#define C2_OFF   1920        // [B]  u32 count targ>shift_t
#define CNTW_OFF 1984        // [2][B][NSLOT] u32 per-wave counts
#define FIX_U32  (1984 + 2*B*NSLOT)
#define BUF_OFF  FIX_U32     // [2][B][NSLOT][capw] f32 candidates

__device__ __forceinline__ uint32_t fmap(float f) {
    uint32_t b = __float_as_uint(f);
    return (b & 0x80000000u) ? ~b : (b | 0x80000000u);
}
__device__ __forceinline__ float funmap(uint32_t u) {
    uint32_t b = (u & 0x80000000u) ? (u & 0x7fffffffu) : ~u;
    return __uint_as_float(b);
}

// ---------------- sample: per-sample 20-bit median bracket from 8192 elems ----------------
__global__ void __launch_bounds__(1024) sample_kernel(const float* __restrict__ pred,
                                                      const float* __restrict__ targ,
                                                      uint32_t* __restrict__ ws) {
    __shared__ uint32_t kp[SCAP], kt[SCAP];
    __shared__ uint32_t h[4096];
    __shared__ uint32_t sc[256];
    __shared__ uint32_t s_ct, s_lo12, s_hi12, s_clo, s_bl, s_bh;
    const int b = blockIdx.x;
    const int t = threadIdx.x;
    const int lane = t & 63;
    if (t == 0) s_ct = 0;
    __syncthreads();
    const float4* pb = (const float4*)(pred + (size_t)b * NPX);
    const float4* tb = (const float4*)(targ + (size_t)b * NPX);
    #pragma unroll
    for (int c = 0; c < 2; c++) {
        int j = t + c * 1024;
        int q = ((j >> 6) * 1536) + (j & 63);
        float4 tv = tb[q], pv = pb[q];
        float tA[4] = {tv.x, tv.y, tv.z, tv.w};
        float pA[4] = {pv.x, pv.y, pv.z, pv.w};
        #pragma unroll
        for (int e = 0; e < 4; e++) {
            bool msk = tA[e] > 0.f;
            unsigned long long bal = __ballot(msk);
            if (bal) {
                int leader = __ffsll((long long)bal) - 1;
                uint32_t base = 0;
                if (lane == leader) base = atomicAdd(&s_ct, (uint32_t)__popcll(bal));
                base = (uint32_t)__shfl((int)base, leader, 64);
                if (msk) {
                    uint32_t off = base + (uint32_t)__popcll(bal & ((1ull << lane) - 1ull));
                    if (off < SCAP) { kt[off] = fmap(tA[e]); kp[off] = fmap(pA[e]); }
                }
            }
        }
    }
    __syncthreads();
    const uint32_t ct = s_ct;
    const bool ok = (ct > 0) && (ct <= SCAP);
    for (int w = 0; w < 2; w++) {
        const uint32_t* K = (w == 0) ? kp : kt;
        uint32_t BL = 0, BH = 0xFFFFFu;
        if (ok) {
            uint32_t rlo = (uint32_t)((0.5f - DELTA) * (float)ct);
            uint32_t rhi = (uint32_t)((0.5f + DELTA) * (float)ct);
            if (rhi >= ct) rhi = ct - 1;
            for (int i = t; i < 4096; i += 1024) h[i] = 0;
            __syncthreads();
            for (uint32_t j = t; j < ct; j += 1024) atomicAdd(&h[K[j] >> 20], 1u);
            __syncthreads();
            uint32_t ms = 0;
            if (t < 256) { for (int i = 0; i < 16; i++) ms += h[t * 16 + i]; sc[t] = ms; }
            __syncthreads();
            for (int off = 1; off < 256; off <<= 1) {
                uint32_t a = (t < 256 && t >= off) ? sc[t - off] : 0u;
                __syncthreads();
                if (t < 256) sc[t] += a;
                __syncthreads();
            }
            if (t < 256) {
                uint32_t incl = sc[t], excl = incl - ms;
                if (rlo >= excl && rlo < incl) {
                    uint32_t c2 = excl;
                    for (int i = 0; i < 16; i++) {
                        uint32_t hv = h[t * 16 + i];
                        if (rlo < c2 + hv) { s_lo12 = t * 16 + i; s_clo = c2; break; }
                        c2 += hv;
                    }
                }
                if (rhi >= excl && rhi < incl) {
                    uint32_t c2 = excl;
                    for (int i = 0; i < 16; i++) {
                        uint32_t hv = h[t * 16 + i];
                        if (rhi < c2 + hv) { s_hi12 = t * 16 + i; break; }
                        c2 += hv;
                    }
                }
            }
            __syncthreads();
            const uint32_t lo12 = s_lo12, hi12 = s_hi12, clo = s_clo;
            const uint32_t range = (hi12 - lo12 + 1) << 8;
            if (range > 4096) {
                BL = lo12 << 8; BH = (hi12 << 8) | 255u;
            } else {
                for (int i = t; i < 4096; i += 1024) h[i] = 0;
                __syncthreads();
                const uint32_t base20 = lo12 << 8;
                for (uint32_t j = t; j < ct; j += 1024) {
                    uint32_t u = K[j], u12 = u >> 20;
                    if (u12 >= lo12 && u12 <= hi12) atomicAdd(&h[(u >> 12) - base20], 1u);
                }
                __syncthreads();
                const uint32_t r2lo = rlo - clo, r2hi = rhi - clo;
                uint32_t ms2 = 0;
                if (t < 256) { for (int i = 0; i < 16; i++) ms2 += h[t * 16 + i]; sc[t] = ms2; }
                __syncthreads();
                for (int off = 1; off < 256; off <<= 1) {
                    uint32_t a = (t < 256 && t >= off) ? sc[t - off] : 0u;
                    __syncthreads();
                    if (t < 256) sc[t] += a;
                    __syncthreads();
                }
                if (t < 256) {
                    uint32_t incl = sc[t], excl = incl - ms2;
                    if (r2lo >= excl && r2lo < incl) {
                        uint32_t c2 = excl;
                        for (int i = 0; i < 16; i++) {
                            uint32_t hv = h[t * 16 + i];
                            if (r2lo < c2 + hv) { s_bl = base20 + t * 16 + i; break; }
                            c2 += hv;
                        }
                    }
                    if (r2hi >= excl && r2hi < incl) {
                        uint32_t c2 = excl;
                        for (int i = 0; i < 16; i++) {
                            uint32_t hv = h[t * 16 + i];
                            if (r2hi < c2 + hv) { s_bh = base20 + t * 16 + i; break; }
                            c2 += hv;
                        }
                    }
                }
                __syncthreads();
                BL = s_bl; BH = s_bh;
            }
        }
        if (t == 0) { ws[BL_OFF + w * B + b] = BL; ws[BH_OFF + w * B + b] = BH; }
        __syncthreads();
    }
}

// ---------------- single full pass: n/sums + below-bracket count/sum + compaction ----------------
// grid (16,B) x 256; 48 elems/thread/array in 3 rounds (R16-measured best)
__global__ void __launch_bounds__(256) collect_kernel(const float* __restrict__ pred,
                                                      const float* __restrict__ targ,
                                                      uint32_t* __restrict__ ws, int capw) {
    const int b = blockIdx.y;
    const int t = threadIdx.x;
    const int lane = t & 63;
    const int slot = (blockIdx.x << 2) + (t >> 6);    // [0,64)
    const uint32_t BLp = ws[BL_OFF + b],     BHp = ws[BH_OFF + b];
    const uint32_t BLt = ws[BL_OFF + B + b], BHt = ws[BH_OFF + B + b];
    const float4* pb = (const float4*)(pred + (size_t)b * NPX);
    const float4* tb = (const float4*)(targ + (size_t)b * NPX);
    const int tid = blockIdx.x * 256 + t;             // [0,4096)
    float* bufp = ((float*)(ws + BUF_OFF)) + ((size_t)b * NSLOT + slot) * capw;
    float* buft = ((float*)(ws + BUF_OFF)) + (((size_t)B + b) * NSLOT + slot) * capw;
    float sbp = 0.f, sbt = 0.f, sump = 0.f, sumt = 0.f;
    uint32_t nloc = 0, cbp = 0, cbt = 0;
    uint32_t wp = 0, wt = 0;                          // wave-uniform running counts
    #pragma unroll
    for (int r = 0; r < 3; r++) {
        float4 ta0 = tb[tid + (4*r+0)*4096], ta1 = tb[tid + (4*r+1)*4096];
        float4 ta2 = tb[tid + (4*r+2)*4096], ta3 = tb[tid + (4*r+3)*4096];
        float4 pa0 = pb[tid + (4*r+0)*4096], pa1 = pb[tid + (4*r+1)*4096];
        float4 pa2 = pb[tid + (4*r+2)*4096], pa3 = pb[tid + (4*r+3)*4096];
        float tA[16] = {ta0.x,ta0.y,ta0.z,ta0.w, ta1.x,ta1.y,ta1.z,ta1.w,
                        ta2.x,ta2.y,ta2.z,ta2.w, ta3.x,ta3.y,ta3.z,ta3.w};
        float pA[16] = {pa0.x,pa0.y,pa0.z,pa0.w, pa1.x,pa1.y,pa1.z,pa1.w,
                        pa2.x,pa2.y,pa2.z,pa2.w, pa3.x,pa3.y,pa3.z,pa3.w};
        uint32_t mbp = 0, mbt = 0;                    // match bitmasks
        #pragma unroll
        for (int e = 0; e < 16; e++) {
            float tv = tA[e], pv = pA[e];
            if (tv > 0.f) {
                nloc++; sumt += tv; sump += pv;
                uint32_t up = fmap(pv) >> 12, ut = fmap(tv) >> 12;
                if (up < BLp) { cbp++; sbp += pv; }
                else if (up <= BHp) mbp |= (1u << e);
                if (ut < BLt) { cbt++; sbt += tv; }
                else if (ut <= BHt) mbt |= (1u << e);
            }
        }
        uint32_t packed = (uint32_t)__popc(mbp) | ((uint32_t)__popc(mbt) << 16);
        uint32_t scan = packed;
        #pragma unroll
        for (int off = 1; off < 64; off <<= 1) {
            uint32_t v = (uint32_t)__shfl_up((int)scan, off, 64);
            if (lane >= off) scan += v;
        }
        uint32_t tot = (uint32_t)__shfl((int)scan, 63, 64);
        uint32_t exl = scan - packed;
        uint32_t op = wp + (exl & 0xFFFFu);
        uint32_t ot = wt + (exl >> 16);
        if (mbp | mbt) {
            #pragma unroll
            for (int e = 0; e < 16; e++) {
                if ((mbp >> e) & 1u) { if (op < (uint32_t)capw) bufp[op] = pA[e]; op++; }
                if ((mbt >> e) & 1u) { if (ot < (uint32_t)capw) buft[ot] = tA[e]; ot++; }
            }
        }
        wp += tot & 0xFFFFu;
        wt += tot >> 16;
    }
    if (lane == 0) {
        ws[CNTW_OFF + b * NSLOT + slot] = wp;
        ws[CNTW_OFF + (B + b) * NSLOT + slot] = wt;
        if (wp > (uint32_t)capw) ws[OVF_OFF + b] = 1u;
        if (wt > (uint32_t)capw) ws[OVF_OFF + B + b] = 1u;
    }
    for (int off = 32; off; off >>= 1) {
        nloc += __shfl_down(nloc, off, 64);
        sump += __shfl_down(sump, off, 64);
        sumt += __shfl_down(sumt, off, 64);
        sbp  += __shfl_down(sbp, off, 64);
        sbt  += __shfl_down(sbt, off, 64);
        cbp  += __shfl_down(cbp, off, 64);
        cbt  += __shfl_down(cbt, off, 64);
    }
    if (lane == 0) {
        if (nloc) atomicAdd(ws + N_OFF + b, nloc);
        atomicAdd(((float*)(ws + TSUM_OFF)) + b, sump);
        atomicAdd(((float*)(ws + TSUM_OFF)) + B + b, sumt);
        atomicAdd(((float*)(ws + SB_OFF)) + b, sbp);
        atomicAdd(((float*)(ws + SB_OFF)) + B + b, sbt);
        if (cbp) atomicAdd(ws + CB_OFF + b, cbp);
        if (cbt) atomicAdd(ws + CB_OFF + B + b, cbt);
    }
}

// ---------------- small select: dense gather -> 3-stage (12+11+9) LDS radix ----------------
__global__ void small3_kernel(const float* __restrict__ pred,
                              const float* __restrict__ targ,
                              uint32_t* __restrict__ ws, int capw) {
    const int b = blockIdx.x, which = blockIdx.y;
    const int t = threadIdx.x;
    __shared__ float dense[CAPD];        // 48 KB
    __shared__ uint32_t cnt[4096];       // 16 KB
    __shared__ float fsm[4096];          // 16 KB
    __shared__ uint32_t sc[256];
    __shared__ float sfl[256];
    __shared__ uint32_t scnt[NSLOT], soff[NSLOT];
    __shared__ uint32_t r_bin, r_k, s_Ctot;
    __shared__ float r_f, s_facc;
    const uint32_t n = ws[N_OFF + b];
    const uint32_t k0 = (n - 1u) >> 1;
    const uint32_t CBv = ws[CB_OFF + which * B + b];
    const uint32_t* cw = ws + CNTW_OFF + (which * B + b) * NSLOT;
    const float* bufb = ((const float*)(ws + BUF_OFF)) + ((size_t)which * B + b) * NSLOT * capw;
    const float* Tp = targ + (size_t)b * NPX;
    const float* Pp = pred + (size_t)b * NPX;

    // ---- gather counts -> prefix -> dense LDS copy ----
    uint32_t myc = (t < NSLOT) ? cw[t] : 0u;
    sc[t] = myc;
    __syncthreads();
    for (int off = 1; off < NSLOT; off <<= 1) {
        uint32_t a = (t >= off) ? sc[t - off] : 0u;
        __syncthreads();
        sc[t] += a;
        __syncthreads();
    }
    if (t < NSLOT) { scnt[t] = myc; soff[t] = sc[t] - myc; }
    if (t == NSLOT - 1) s_Ctot = sc[t];
    __syncthreads();
    const uint32_t Ctot = s_Ctot;
    const long k_in = (long)k0 - (long)CBv;
    const bool fast = (capw > 0) && (ws[OVF_OFF + which * B + b] == 0u) &&
                      (Ctot <= (uint32_t)CAPD) && (k_in >= 0) && (k_in < (long)Ctot);
    if (fast) {
        const int s = t >> 2;                        // 4 threads per slot
        const float* sb_ = bufb + (size_t)s * capw;
        const uint32_t nn = scnt[s], o = soff[s];
        for (uint32_t j = (uint32_t)(t & 3); j < nn; j += 4) dense[o + j] = sb_[j];
    }
    __syncthreads();

    uint32_t kr = fast ? (uint32_t)k_in : k0;

    // ---- stage 0: top 12 bits ----
    for (int i = t; i < 4096; i += 256) { cnt[i] = 0; fsm[i] = 0.f; }
    __syncthreads();
    if (fast) {
        for (uint32_t j = t; j < Ctot; j += 256) {
            float v = dense[j];
            uint32_t key = fmap(v) >> 20;
            atomicAdd(&cnt[key], 1u); atomicAdd(&fsm[key], v);
        }
    } else {
        for (int j = t; j < NPX; j += 256) {
            float tvv = Tp[j];
            if (tvv > 0.f) {
                float v = (which == 0) ? Pp[j] : tvv;
                uint32_t key = fmap(v) >> 20;
                atomicAdd(&cnt[key], 1u); atomicAdd(&fsm[key], v);
            }
        }
    }
    __syncthreads();
    {
        uint32_t ms = 0; float mf = 0.f;
        #pragma unroll
        for (int i = 0; i < 16; i++) { ms += cnt[t * 16 + i]; mf += fsm[t * 16 + i]; }
        sc[t] = ms; sfl[t] = mf;
        __syncthreads();
        for (int off = 1; off < 256; off <<= 1) {
            uint32_t a = (t >= off) ? sc[t - off] : 0u;
            float af = (t >= off) ? sfl[t - off] : 0.f;
            __syncthreads();
            sc[t] += a; sfl[t] += af;
            __syncthreads();
        }
        uint32_t incl = sc[t], excl = incl - ms;
        float fx = sfl[t] - mf;
        if (kr >= excl && kr < incl) {
            uint32_t c = excl, bin = 0, nk = 0; float f = fx;
            for (int i = 0; i < 16; i++) {
                uint32_t hv = cnt[t * 16 + i];
                if (kr < c + hv) { bin = t * 16 + i; nk = kr - c; break; }
                c += hv; f += fsm[t * 16 + i];
            }
            r_bin = bin; r_k = nk; r_f = f;
        }
    }
    __syncthreads();
    const uint32_t sel0 = r_bin;
    kr = r_k;
    if (t == 0) s_facc = r_f;
    __syncthreads();

    // ---- stage 1: mid 11 bits within sel0 ----
    for (int i = t; i < NBA; i += 256) { cnt[i] = 0; fsm[i] = 0.f; }
    __syncthreads();
    if (fast) {
        for (uint32_t j = t; j < Ctot; j += 256) {
            float v = dense[j];
            uint32_t u = fmap(v);
            if ((u >> 20) == sel0) {
                uint32_t key = (u >> 9) & (NBA - 1u);
                atomicAdd(&cnt[key], 1u); atomicAdd(&fsm[key], v);
            }
        }
    } else {
        for (int j = t; j < NPX; j += 256) {
            float tvv = Tp[j];
            if (tvv > 0.f) {
                float v = (which == 0) ? Pp[j] : tvv;
                uint32_t u = fmap(v);
                if ((u >> 20) == sel0) {
                    uint32_t key = (u >> 9) & (NBA - 1u);
                    atomicAdd(&cnt[key], 1u); atomicAdd(&fsm[key], v);
                }
            }
        }
    }
    __syncthreads();
    {
        uint32_t ms = 0; float mf = 0.f;
        #pragma unroll
        for (int i = 0; i < 8; i++) { ms += cnt[t * 8 + i]; mf += fsm[t * 8 + i]; }
        sc[t] = ms; sfl[t] = mf;
        __syncthreads();
        for (int off = 1; off < 256; off <<= 1) {
            uint32_t a = (t >= off) ? sc[t - off] : 0u;
            float af = (t >= off) ? sfl[t - off] : 0.f;
            __syncthreads();
            sc[t] += a; sfl[t] += af;
            __syncthreads();
        }
        uint32_t incl = sc[t], excl = incl - ms;
        float fx = sfl[t] - mf;
        if (kr >= excl && kr < incl) {
            uint32_t c = excl, bin = 0, nk = 0; float f = fx;
            for (int i = 0; i < 8; i++) {
                uint32_t hv = cnt[t * 8 + i];
                if (kr < c + hv) { bin = t * 8 + i; nk = kr - c; break; }
                c += hv; f += fsm[t * 8 + i];
            }
            r_bin = bin; r_k = nk; r_f = f;
        }
    }
    __syncthreads();
    const uint32_t pfx23 = (sel0 << 11) | r_bin;
    kr = r_k;
    if (t == 0) s_facc += r_f;
    __syncthreads();

    // ---- stage 2: low 9 bits ----
    for (int i = t; i < 512; i += 256) { cnt[i] = 0; fsm[i] = 0.f; }
    __syncthreads();
    if (fast) {
        for (uint32_t j = t; j < Ctot; j += 256) {
            float v = dense[j];
            uint32_t u = fmap(v);
            if ((u >> 9) == pfx23) {
                uint32_t key = u & 511u;
                atomicAdd(&cnt[key], 1u); atomicAdd(&fsm[key], v);
            }
        }
    } else {
        for (int j = t; j < NPX; j += 256) {
            float tvv = Tp[j];
            if (tvv > 0.f) {
                float v = (which == 0) ? Pp[j] : tvv;
                uint32_t u = fmap(v);
                if ((u >> 9) == pfx23) {
                    uint32_t key = u & 511u;
                    atomicAdd(&cnt[key], 1u); atomicAdd(&fsm[key], v);
                }
            }
        }
    }
    __syncthreads();
    {
        uint32_t ms = 0; float mf = 0.f;
        #pragma unroll
        for (int i = 0; i < 2; i++) { ms += cnt[t * 2 + i]; mf += fsm[t * 2 + i]; }
        sc[t] = ms; sfl[t] = mf;
        __syncthreads();
        for (int off = 1; off < 256; off <<= 1) {
            uint32_t a = (t >= off) ? sc[t - off] : 0u;
            float af = (t >= off) ? sfl[t - off] : 0.f;
            __syncthreads();
            sc[t] += a; sfl[t] += af;
            __syncthreads();
        }
        uint32_t incl = sc[t], excl = incl - ms;
        float fx = sfl[t] - mf;
        if (kr >= excl && kr < incl) {
            uint32_t c = excl, bin = 0, nk = 0, e = 0; float f = fx;
            for (int i = 0; i < 2; i++) {
                uint32_t hv = cnt[t * 2 + i];
                if (kr < c + hv) { bin = t * 2 + i; nk = kr - c; e = hv; break; }
                c += hv; f += fsm[t * 2 + i];
            }
            uint32_t u = (pfx23 << 9) | bin;
            ((float*)(ws + SH_OFF))[which * B + b] = funmap(u);
            ws[K_OFF + which * B + b] = nk;      // k3
            ws[EQ_OFF + which * B + b] = e;
            float* sb = ((float*)(ws + SB_OFF)) + which * B + b;
            float below = s_facc + f;
            *sb = fast ? (*sb + below) : below;
        }
    }
}

// ---------------- params ----------------
__global__ void param_kernel(const float* __restrict__ pred,
                             const float* __restrict__ targ,
                             uint32_t* __restrict__ ws) {
    const int b = threadIdx.x;
    if (b >= B) return;
    const uint32_t n = ws[N_OFF + b];
    const uint32_t k0 = (n - 1u) >> 1;
    float med[2], rs[2];
    uint32_t nab[2];
    #pragma unroll
    for (int w = 0; w < 2; w++) {
        float m = ((const float*)(ws + SH_OFF))[w * B + b];
        uint32_t k3 = ws[K_OFF + w * B + b];
        uint32_t e = ws[EQ_OFF + w * B + b];
        float SBv = ((const float*)(ws + SB_OFF))[w * B + b];
        float ST = ((const float*)(ws + TSUM_OFF))[w * B + b];
        uint32_t CB = k0 - k3;
        uint32_t na = n - CB - e;
        float Sab = ST - SBv - (float)e * m;
        float absdev = (Sab - (float)na * m) + ((float)CB * m - SBv);
        float scale = absdev / (float)n;
        med[w] = m; nab[w] = na;
        rs[w] = 1.f / scale;
        ((float*)(ws + RS_OFF))[w * B + b] = rs[w];
    }
    uint32_t c2 = nab[1];
    ws[C2_OFF + b] = c2;
    uint32_t mi = (uint32_t)NPX - c2 + (uint32_t)TRIM_IDX;
    if (mi > (uint32_t)(NPX - 1)) mi = NPX - 1;
    float p = pred[(size_t)b * NPX + mi];
    float t = targ[(size_t)b * NPX + mi];
    float pn = (p - med[0]) * rs[0], tn = (t - med[1]) * rs[1];
    ((float*)(ws + THR_OFF))[b] = (tn > 0.f) ? fabsf(pn - tn) : 0.f;
}

// ---------------- fused loss: 8-row strip per wave, 2-deep register ring ----------------
__global__ void __launch_bounds__(256) loss_kernel(const float* __restrict__ pred,
                                                   const float* __restrict__ targ,
                                                   uint32_t* __restrict__ ws) {
    const int wid = (blockIdx.x << 2) + (threadIdx.x >> 6);
    const int b = wid / (H / RPW);
    const int s0 = (wid - b * (H / RPW)) * RPW;
    const int l = threadIdx.x & 63;
    const int col = l << 3;
    const float sp = ((const float*)(ws + SH_OFF))[b];
    const float st = ((const float*)(ws + SH_OFF))[B + b];
    const float rp = ((const float*)(ws + RS_OFF))[b];
    const float rt = ((const float*)(ws + RS_OFF))[B + b];
    const float thr = ((const float*)(ws + THR_OFF))[b];
    const float* Pp = pred + (size_t)b * NPX;
    const float* Tp = targ + (size_t)b * NPX;

    const bool g1 = s0 >= 1, g2 = s0 >= 2, g4 = s0 >= 4, g8 = s0 >= 8;
    float rT[2][8], rPN[2][8];
    {
        const int roA = (g1 ? (s0 - 1) : s0) * W + col;
        const int roB = (g2 ? (s0 - 2) : s0) * W + col;
        float4 a0 = *(const float4*)(Tp + roA), a1 = *(const float4*)(Tp + roA + 4);
        float4 b0 = *(const float4*)(Pp + roA), b1 = *(const float4*)(Pp + roA + 4);
        float4 c0 = *(const float4*)(Tp + roB), c1 = *(const float4*)(Tp + roB + 4);
        float4 d0 = *(const float4*)(Pp + roB), d1 = *(const float4*)(Pp + roB + 4);
        float ta[8] = {a0.x,a0.y,a0.z,a0.w,a1.x,a1.y,a1.z,a1.w};
        float pa[8] = {b0.x,b0.y,b0.z,b0.w,b1.x,b1.y,b1.z,b1.w};
        float tc[8] = {c0.x,c0.y,c0.z,c0.w,c1.x,c1.y,c1.z,c1.w};
        float pc[8] = {d0.x,d0.y,d0.z,d0.w,d1.x,d1.y,d1.z,d1.w};
        #pragma unroll
        for (int k = 0; k < 8; k++) {
            rT[1][k] = ta[k]; rPN[1][k] = (pa[k] - sp) * rp;
            rT[0][k] = tc[k]; rPN[0][k] = (pc[k] - sp) * rp;
        }
    }

    float tl = 0.f, gl0 = 0.f, gl1 = 0.f, gl2 = 0.f, gl3 = 0.f;
    uint32_t mc = 0;

    #pragma unroll
    for (int it = 0; it < RPW; ++it) {
        const int ro = (s0 + it) * W + col;
        const int cur = it & 1, prv = cur ^ 1;
        float4 a0 = *(const float4*)(Tp + ro), a1 = *(const float4*)(Tp + ro + 4);
        float4 b0 = *(const float4*)(Pp + ro), b1 = *(const float4*)(Pp + ro + 4);
        float t[8] = {a0.x,a0.y,a0.z,a0.w,a1.x,a1.y,a1.z,a1.w};
        float p[8] = {b0.x,b0.y,b0.z,b0.w,b1.x,b1.y,b1.z,b1.w};
        float t4a = 0.f, t4b = 0.f, p4a = 0.f, p4b = 0.f, t8a = 0.f, p8a = 0.f;
        if (it == 0) {
            const int ro4 = g4 ? ro - 4 * W : ro;
            t4a = Tp[ro4]; t4b = Tp[ro4 + 4]; p4a = Pp[ro4]; p4b = Pp[ro4 + 4];
            const int ro8 = g8 ? ro - 8 * W : ro;
            t8a = Tp[ro8]; p8a = Pp[ro8];
        }
        if (it == 4) {
            const int ro4 = ro - 4 * W;
            t4a = Tp[ro4]; t4b = Tp[ro4 + 4]; p4a = Pp[ro4]; p4b = Pp[ro4 + 4];
        }
        float pn[8]; bool m[8];
        #pragma unroll
        for (int k = 0; k < 8; k++) { pn[k] = (p[k] - sp) * rp; m[k] = t[k] > st; }

        #pragma unroll
        for (int k = 0; k < 8; k++) {
            if (m[k]) {
                float tn = (t[k] - st) * rt;
                float r = fabsf(pn[k] - tn);
                if (r <= thr) tl += r;
            }
        }
        float t7p = __shfl_up(t[7], 1), pn7p = __shfl_up(pn[7], 1);
        if (l > 0 && m[0] && t7p > st) gl0 += fabsf(pn[0] - pn7p);
        #pragma unroll
        for (int k = 1; k < 8; k++) if (m[k] && m[k - 1]) gl0 += fabsf(pn[k] - pn[k - 1]);
        if (it > 0 || g1) {
            #pragma unroll
            for (int k = 0; k < 8; k++)
                if (m[k] && rT[prv][k] > st) gl0 += fabsf(pn[k] - rPN[prv][k]);
        }
        if ((it & 1) == 0) {
            float t6p = __shfl_up(t[6], 1), pn6p = __shfl_up(pn[6], 1);
            mc += (uint32_t)m[0] + m[2] + m[4] + m[6];
            if (l > 0 && m[0] && t6p > st) gl1 += fabsf(pn[0] - pn6p);
            if (m[2] && m[0]) gl1 += fabsf(pn[2] - pn[0]);
            if (m[4] && m[2]) gl1 += fabsf(pn[4] - pn[2]);
            if (m[6] && m[4]) gl1 += fabsf(pn[6] - pn[4]);
            if (it >= 2 || g2) {
                if (m[0] && rT[cur][0] > st) gl1 += fabsf(pn[0] - rPN[cur][0]);
                if (m[2] && rT[cur][2] > st) gl1 += fabsf(pn[2] - rPN[cur][2]);
                if (m[4] && rT[cur][4] > st) gl1 += fabsf(pn[4] - rPN[cur][4]);
                if (m[6] && rT[cur][6] > st) gl1 += fabsf(pn[6] - rPN[cur][6]);
            }
            if ((it & 3) == 0) {
                float t4p = __shfl_up(t[4], 1), pn4p = __shfl_up(pn[4], 1);
                mc += ((uint32_t)m[0] + m[4]) << 11;
                if (l > 0 && m[0] && t4p > st) gl2 += fabsf(pn[0] - pn4p);
                if (m[4] && m[0]) gl2 += fabsf(pn[4] - pn[0]);
                if (it == 4 || g4) {
                    if (m[0] && t4a > st) gl2 += fabsf(pn[0] - (p4a - sp) * rp);
                    if (m[4] && t4b > st) gl2 += fabsf(pn[4] - (p4b - sp) * rp);
                }
                if (it == 0) {
                    float t0p = __shfl_up(t[0], 1), pn0p = __shfl_up(pn[0], 1);
                    mc += ((uint32_t)m[0]) << 22;
                    if (l > 0 && m[0] && t0p > st) gl3 += fabsf(pn[0] - pn0p);
                    if (g8 && m[0] && t8a > st) gl3 += fabsf(pn[0] - (p8a - sp) * rp);
                }
            }
        }
        #pragma unroll
        for (int k = 0; k < 8; k++) { rT[cur][k] = t[k]; rPN[cur][k] = pn[k]; }
    }

    for (int off = 32; off; off >>= 1) {
        tl  += __shfl_down(tl, off, 64);
        gl0 += __shfl_down(gl0, off, 64);
        gl1 += __shfl_down(gl1, off, 64);
        gl2 += __shfl_down(gl2, off, 64);
        gl3 += __shfl_down(gl3, off, 64);
        mc  += __shfl_down(mc, off, 64);
    }
    if (l == 0) {
        float* gs = (float*)(ws + GS_OFF);
        atomicAdd(((float*)(ws + TS_OFF)) + b, tl);
        atomicAdd(gs + b, gl0);
        atomicAdd(gs + B + b, gl1);
        atomicAdd(gs + 2 * B + b, gl2);
        atomicAdd(gs + 3 * B + b, gl3);
        atomicAdd(ws + MS_OFF + b, mc & 0x7FFu);
        atomicAdd(ws + MS_OFF + B + b, (mc >> 11) & 0x7FFu);
        atomicAdd(ws + MS_OFF + 2 * B + b, mc >> 22);
    }
}

// ---------------- finalize ----------------
__global__ void finalize_kernel(const uint32_t* __restrict__ ws, float* __restrict__ out) {
    const int b = threadIdx.x;
    float v = 0.f;
    if (b < B) {
        float c2 = (float)ws[C2_OFF + b];
        const float* tsum = (const float*)(ws + TS_OFF);
        const float* gsum = (const float*)(ws + GS_OFF);
        float tm = (c2 > 0.f) ? tsum[b] / (2.f * c2) : 0.f;
        float g = (c2 > 0.f) ? gsum[b] / c2 : 0.f;
        for (int z = 0; z < 3; z++) {
            float ms = (float)ws[MS_OFF + z * B + b];
            g += (ms > 0.f) ? gsum[(1 + z) * B + b] / ms : 0.f;
        }
        v = tm + 0.5f * g;
    }
    for (int off = 32; off; off >>= 1) v += __shfl_down(v, off, 64);
    if (b == 0) out[0] = v * (1.f / 64.f);
}

extern "C" void kernel_launch(void* const* d_in, const int* in_sizes, int n_in,
                              void* d_out, int out_size, void* d_ws, size_t ws_size,
                              hipStream_t stream) {
    const float* pred = (const float*)d_in[0];
    const float* targ = (const float*)d_in[1];
    float* out = (float*)d_out;
    uint32_t* ws = (uint32_t*)d_ws;

    long avail = (long)(ws_size / 4) - (long)FIX_U32;
    int capw = 0;
    if (avail > 0) {
        long c = avail / (2L * B * NSLOT);
        capw = (int)(c < CAPW ? c : CAPW);
    }

    hipMemsetAsync(ws, 0, (size_t)ZERO_U32 * 4, stream);

    sample_kernel<<<dim3(B), 1024, 0, stream>>>(pred, targ, ws);
    collect_kernel<<<dim3(16, B), 256, 0, stream>>>(pred, targ, ws, capw);
    small3_kernel<<<dim3(B, 2), 256, 0, stream>>>(pred, targ, ws, capw);
    param_kernel<<<1, 64, 0, stream>>>(pred, targ, ws);
    loss_kernel<<<dim3(B * (H / RPW) / 4), 256, 0, stream>>>(pred, targ, ws);
    finalize_kernel<<<1, 64, 0, stream>>>(ws, out);
}

// Round 19
// 139.345 us; speedup vs baseline: 1.7197x; 1.0549x over previous
//
#include <hip/hip_runtime.h>
#include <stdint.h>

#define B 64
#define H 384
#define W 512
#define NPX (H*W)            // 196608
#define TRIM_IDX 157286      // int(0.8 * 196608)
#define RPW 8                // rows per wave in loss kernel

#define NBA 2048
#define CAPW 256             // per-wave candidate cap
#define NSLOT 64             // waves per sample in collect
#define CAPD 12288           // dense LDS candidate cap in small3 (48 KB)
#define SCAP 6144            // sample stash cap
#define DELTA 0.03f          // sample-quantile half-window

// ---- workspace layout (uint32 units) ----
#define N_OFF    0           // [B]  u32 mask count
#define MS_OFF   64          // [3][B] u32 subsample mask counts
#define TS_OFF   256         // [B]  f32 tmae sum
#define GS_OFF   320         // [4][B] f32 grad sums
#define TSUM_OFF 576         // [2][B] f32 total masked value sum
#define SB_OFF   704         // [2][B] f32 sum below (bracket, then median)
#define CB_OFF   832         // [2][B] u32 count below bracket
#define OVF_OFF  960         // [2][B] u32 overflow flag
// persistent (written before read each launch)
#define BL_OFF   1088        // [2][B] u32 bracket lo (20-bit prefix)
#define BH_OFF   1216        // [2][B] u32 bracket hi
#define K_OFF    1344        // [2][B] u32 k3 (rank within final value)
#define EQ_OFF   1472        // [2][B] u32 count equal to median
#define SH_OFF   1600        // [2][B] f32 median (shift)
#define THR_OFF  1856        // [B]  f32 (unused scratch)
#define C2_OFF   1920        // [B]  u32 count targ>shift_t
#define CNTW_OFF 1984        // [2][B][NSLOT] u32 per-wave counts
#define FIX_U32  (1984 + 2*B*NSLOT)
#define BUF_OFF  FIX_U32     // [2][B][NSLOT][capw] f32 candidates

__device__ __forceinline__ uint32_t fmap(float f) {
    uint32_t b = __float_as_uint(f);
    return (b & 0x80000000u) ? ~b : (b | 0x80000000u);
}
__device__ __forceinline__ float funmap(uint32_t u) {
    uint32_t b = (u & 0x80000000u) ? (u & 0x7fffffffu) : ~u;
    return __uint_as_float(b);
}

// ---------------- sample: zero accumulators + 20-bit median bracket from 8192 elems ----------------
__global__ void __launch_bounds__(1024) sample_kernel(const float* __restrict__ pred,
                                                      const float* __restrict__ targ,
                                                      uint32_t* __restrict__ ws) {
    __shared__ uint32_t kp[SCAP], kt[SCAP];
    __shared__ uint32_t h[4096];
    __shared__ uint32_t sc[256];
    __shared__ uint32_t s_ct, s_lo12, s_hi12, s_clo, s_bl, s_bh;
    const int b = blockIdx.x;
    const int t = threadIdx.x;
    const int lane = t & 63;
    if (t == 0) {
        s_ct = 0;
        // fold memset: zero this sample's accumulator slots (visible to later kernels)
        ws[N_OFF + b] = 0; ws[TS_OFF + b] = 0;
        #pragma unroll
        for (int z = 0; z < 3; z++) ws[MS_OFF + z * B + b] = 0;
        #pragma unroll
        for (int w2 = 0; w2 < 4; w2++) ws[GS_OFF + w2 * B + b] = 0;
        #pragma unroll
        for (int w2 = 0; w2 < 2; w2++) {
            ws[TSUM_OFF + w2 * B + b] = 0;
            ws[SB_OFF + w2 * B + b] = 0;
            ws[CB_OFF + w2 * B + b] = 0;
            ws[OVF_OFF + w2 * B + b] = 0;
        }
    }
    __syncthreads();
    const float4* pb = (const float4*)(pred + (size_t)b * NPX);
    const float4* tb = (const float4*)(targ + (size_t)b * NPX);
    #pragma unroll
    for (int c = 0; c < 2; c++) {
        int j = t + c * 1024;
        int q = ((j >> 6) * 1536) + (j & 63);
        float4 tv = tb[q], pv = pb[q];
        float tA[4] = {tv.x, tv.y, tv.z, tv.w};
        float pA[4] = {pv.x, pv.y, pv.z, pv.w};
        #pragma unroll
        for (int e = 0; e < 4; e++) {
            bool msk = tA[e] > 0.f;
            unsigned long long bal = __ballot(msk);
            if (bal) {
                int leader = __ffsll((long long)bal) - 1;
                uint32_t base = 0;
                if (lane == leader) base = atomicAdd(&s_ct, (uint32_t)__popcll(bal));
                base = (uint32_t)__shfl((int)base, leader, 64);
                if (msk) {
                    uint32_t off = base + (uint32_t)__popcll(bal & ((1ull << lane) - 1ull));
                    if (off < SCAP) { kt[off] = fmap(tA[e]); kp[off] = fmap(pA[e]); }
                }
            }
        }
    }
    __syncthreads();
    const uint32_t ct = s_ct;
    const bool ok = (ct > 0) && (ct <= SCAP);
    for (int w = 0; w < 2; w++) {
        const uint32_t* K = (w == 0) ? kp : kt;
        uint32_t BL = 0, BH = 0xFFFFFu;
        if (ok) {
            uint32_t rlo = (uint32_t)((0.5f - DELTA) * (float)ct);
            uint32_t rhi = (uint32_t)((0.5f + DELTA) * (float)ct);
            if (rhi >= ct) rhi = ct - 1;
            for (int i = t; i < 4096; i += 1024) h[i] = 0;
            __syncthreads();
            for (uint32_t j = t; j < ct; j += 1024) atomicAdd(&h[K[j] >> 20], 1u);
            __syncthreads();
            uint32_t ms = 0;
            if (t < 256) { for (int i = 0; i < 16; i++) ms += h[t * 16 + i]; sc[t] = ms; }
            __syncthreads();
            for (int off = 1; off < 256; off <<= 1) {
                uint32_t a = (t < 256 && t >= off) ? sc[t - off] : 0u;
                __syncthreads();
                if (t < 256) sc[t] += a;
                __syncthreads();
            }
            if (t < 256) {
                uint32_t incl = sc[t], excl = incl - ms;
                if (rlo >= excl && rlo < incl) {
                    uint32_t c2 = excl;
                    for (int i = 0; i < 16; i++) {
                        uint32_t hv = h[t * 16 + i];
                        if (rlo < c2 + hv) { s_lo12 = t * 16 + i; s_clo = c2; break; }
                        c2 += hv;
                    }
                }
                if (rhi >= excl && rhi < incl) {
                    uint32_t c2 = excl;
                    for (int i = 0; i < 16; i++) {
                        uint32_t hv = h[t * 16 + i];
                        if (rhi < c2 + hv) { s_hi12 = t * 16 + i; break; }
                        c2 += hv;
                    }
                }
            }
            __syncthreads();
            const uint32_t lo12 = s_lo12, hi12 = s_hi12, clo = s_clo;
            const uint32_t range = (hi12 - lo12 + 1) << 8;
            if (range > 4096) {
                BL = lo12 << 8; BH = (hi12 << 8) | 255u;
            } else {
                for (int i = t; i < 4096; i += 1024) h[i] = 0;
                __syncthreads();
                const uint32_t base20 = lo12 << 8;
                for (uint32_t j = t; j < ct; j += 1024) {
                    uint32_t u = K[j], u12 = u >> 20;
                    if (u12 >= lo12 && u12 <= hi12) atomicAdd(&h[(u >> 12) - base20], 1u);
                }
                __syncthreads();
                const uint32_t r2lo = rlo - clo, r2hi = rhi - clo;
                uint32_t ms2 = 0;
                if (t < 256) { for (int i = 0; i < 16; i++) ms2 += h[t * 16 + i]; sc[t] = ms2; }
                __syncthreads();
                for (int off = 1; off < 256; off <<= 1) {
                    uint32_t a = (t < 256 && t >= off) ? sc[t - off] : 0u;
                    __syncthreads();
                    if (t < 256) sc[t] += a;
                    __syncthreads();
                }
                if (t < 256) {
                    uint32_t incl = sc[t], excl = incl - ms2;
                    if (r2lo >= excl && r2lo < incl) {
                        uint32_t c2 = excl;
                        for (int i = 0; i < 16; i++) {
                            uint32_t hv = h[t * 16 + i];
                            if (r2lo < c2 + hv) { s_bl = base20 + t * 16 + i; break; }
                            c2 += hv;
                        }
                    }
                    if (r2hi >= excl && r2hi < incl) {
                        uint32_t c2 = excl;
                        for (int i = 0; i < 16; i++) {
                            uint32_t hv = h[t * 16 + i];
                            if (r2hi < c2 + hv) { s_bh = base20 + t * 16 + i; break; }
                            c2 += hv;
                        }
                    }
                }
                __syncthreads();
                BL = s_bl; BH = s_bh;
            }
        }
        if (t == 0) { ws[BL_OFF + w * B + b] = BL; ws[BH_OFF + w * B + b] = BH; }
        __syncthreads();
    }
}

// ---------------- single full pass: n/sums + below-bracket count/sum + compaction ----------------
// grid (16,B) x 256; 48 elems/thread in 3 rounds; block-contiguous 48KB windows
__global__ void __launch_bounds__(256) collect_kernel(const float* __restrict__ pred,
                                                      const float* __restrict__ targ,
                                                      uint32_t* __restrict__ ws, int capw) {
    const int b = blockIdx.y;
    const int t = threadIdx.x;
    const int lane = t & 63;
    const int slot = (blockIdx.x << 2) + (t >> 6);    // [0,64)
    const uint32_t BLp = ws[BL_OFF + b],     BHp = ws[BH_OFF + b];
    const uint32_t BLt = ws[BL_OFF + B + b], BHt = ws[BH_OFF + B + b];
    const float4* pb = (const float4*)(pred + (size_t)b * NPX);
    const float4* tb = (const float4*)(targ + (size_t)b * NPX);
    const int bbase = blockIdx.x * 3072;              // float4 units; block window = 48KB/array
    float* bufp = ((float*)(ws + BUF_OFF)) + ((size_t)b * NSLOT + slot) * capw;
    float* buft = ((float*)(ws + BUF_OFF)) + (((size_t)B + b) * NSLOT + slot) * capw;
    float sbp = 0.f, sbt = 0.f, sump = 0.f, sumt = 0.f;
    uint32_t nloc = 0, cbp = 0, cbt = 0;
    uint32_t wp = 0, wt = 0;                          // wave-uniform running counts
    #pragma unroll
    for (int r = 0; r < 3; r++) {
        const int rb = bbase + (4 * r) * 256 + t;
        float4 ta0 = tb[rb], ta1 = tb[rb + 256], ta2 = tb[rb + 512], ta3 = tb[rb + 768];
        float4 pa0 = pb[rb], pa1 = pb[rb + 256], pa2 = pb[rb + 512], pa3 = pb[rb + 768];
        float tA[16] = {ta0.x,ta0.y,ta0.z,ta0.w, ta1.x,ta1.y,ta1.z,ta1.w,
                        ta2.x,ta2.y,ta2.z,ta2.w, ta3.x,ta3.y,ta3.z,ta3.w};
        float pA[16] = {pa0.x,pa0.y,pa0.z,pa0.w, pa1.x,pa1.y,pa1.z,pa1.w,
                        pa2.x,pa2.y,pa2.z,pa2.w, pa3.x,pa3.y,pa3.z,pa3.w};
        uint32_t mbp = 0, mbt = 0;                    // match bitmasks
        #pragma unroll
        for (int e = 0; e < 16; e++) {
            float tv = tA[e], pv = pA[e];
            if (tv > 0.f) {
                nloc++; sumt += tv; sump += pv;
                uint32_t up = fmap(pv) >> 12, ut = fmap(tv) >> 12;
                if (up < BLp) { cbp++; sbp += pv; }
                else if (up <= BHp) mbp |= (1u << e);
                if (ut < BLt) { cbt++; sbt += tv; }
                else if (ut <= BHt) mbt |= (1u << e);
            }
        }
        uint32_t packed = (uint32_t)__popc(mbp) | ((uint32_t)__popc(mbt) << 16);
        uint32_t scan = packed;
        #pragma unroll
        for (int off = 1; off < 64; off <<= 1) {
            uint32_t v = (uint32_t)__shfl_up((int)scan, off, 64);
            if (lane >= off) scan += v;
        }
        uint32_t tot = (uint32_t)__shfl((int)scan, 63, 64);
        uint32_t exl = scan - packed;
        uint32_t op = wp + (exl & 0xFFFFu);
        uint32_t ot = wt + (exl >> 16);
        if (mbp | mbt) {
            #pragma unroll
            for (int e = 0; e < 16; e++) {
                if ((mbp >> e) & 1u) { if (op < (uint32_t)capw) bufp[op] = pA[e]; op++; }
                if ((mbt >> e) & 1u) { if (ot < (uint32_t)capw) buft[ot] = tA[e]; ot++; }
            }
        }
        wp += tot & 0xFFFFu;
        wt += tot >> 16;
    }
    if (lane == 0) {
        ws[CNTW_OFF + b * NSLOT + slot] = wp;
        ws[CNTW_OFF + (B + b) * NSLOT + slot] = wt;
        if (wp > (uint32_t)capw) ws[OVF_OFF + b] = 1u;
        if (wt > (uint32_t)capw) ws[OVF_OFF + B + b] = 1u;
    }
    for (int off = 32; off; off >>= 1) {
        nloc += __shfl_down(nloc, off, 64);
        sump += __shfl_down(sump, off, 64);
        sumt += __shfl_down(sumt, off, 64);
        sbp  += __shfl_down(sbp, off, 64);
        sbt  += __shfl_down(sbt, off, 64);
        cbp  += __shfl_down(cbp, off, 64);
        cbt  += __shfl_down(cbt, off, 64);
    }
    if (lane == 0) {
        if (nloc) atomicAdd(ws + N_OFF + b, nloc);
        atomicAdd(((float*)(ws + TSUM_OFF)) + b, sump);
        atomicAdd(((float*)(ws + TSUM_OFF)) + B + b, sumt);
        atomicAdd(((float*)(ws + SB_OFF)) + b, sbp);
        atomicAdd(((float*)(ws + SB_OFF)) + B + b, sbt);
        if (cbp) atomicAdd(ws + CB_OFF + b, cbp);
        if (cbt) atomicAdd(ws + CB_OFF + B + b, cbt);
    }
}

// ---------------- small select: dense gather -> 3-stage (12+11+9) LDS radix ----------------
__global__ void small3_kernel(const float* __restrict__ pred,
                              const float* __restrict__ targ,
                              uint32_t* __restrict__ ws, int capw) {
    const int b = blockIdx.x, which = blockIdx.y;
    const int t = threadIdx.x;
    __shared__ float dense[CAPD];        // 48 KB
    __shared__ uint32_t cnt[4096];       // 16 KB
    __shared__ float fsm[4096];          // 16 KB
    __shared__ uint32_t sc[256];
    __shared__ float sfl[256];
    __shared__ uint32_t scnt[NSLOT], soff[NSLOT];
    __shared__ uint32_t r_bin, r_k, s_Ctot;
    __shared__ float r_f, s_facc;
    const uint32_t n = ws[N_OFF + b];
    const uint32_t k0 = (n - 1u) >> 1;
    const uint32_t CBv = ws[CB_OFF + which * B + b];
    const uint32_t* cw = ws + CNTW_OFF + (which * B + b) * NSLOT;
    const float* bufb = ((const float*)(ws + BUF_OFF)) + ((size_t)which * B + b) * NSLOT * capw;
    const float* Tp = targ + (size_t)b * NPX;
    const float* Pp = pred + (size_t)b * NPX;

    // ---- gather counts -> prefix -> dense LDS copy ----
    uint32_t myc = (t < NSLOT) ? cw[t] : 0u;
    sc[t] = myc;
    __syncthreads();
    for (int off = 1; off < NSLOT; off <<= 1) {
        uint32_t a = (t >= off) ? sc[t - off] : 0u;
        __syncthreads();
        sc[t] += a;
        __syncthreads();
    }
    if (t < NSLOT) { scnt[t] = myc; soff[t] = sc[t] - myc; }
    if (t == NSLOT - 1) s_Ctot = sc[t];
    __syncthreads();
    const uint32_t Ctot = s_Ctot;
    const long k_in = (long)k0 - (long)CBv;
    const bool fast = (capw > 0) && (ws[OVF_OFF + which * B + b] == 0u) &&
                      (Ctot <= (uint32_t)CAPD) && (k_in >= 0) && (k_in < (long)Ctot);
    if (fast) {
        const int s = t >> 2;                        // 4 threads per slot
        const float* sb_ = bufb + (size_t)s * capw;
        const uint32_t nn = scnt[s], o = soff[s];
        for (uint32_t j = (uint32_t)(t & 3); j < nn; j += 4) dense[o + j] = sb_[j];
    }
    __syncthreads();

    uint32_t kr = fast ? (uint32_t)k_in : k0;

    // ---- stage 0: top 12 bits ----
    for (int i = t; i < 4096; i += 256) { cnt[i] = 0; fsm[i] = 0.f; }
    __syncthreads();
    if (fast) {
        for (uint32_t j = t; j < Ctot; j += 256) {
            float v = dense[j];
            uint32_t key = fmap(v) >> 20;
            atomicAdd(&cnt[key], 1u); atomicAdd(&fsm[key], v);
        }
    } else {
        for (int j = t; j < NPX; j += 256) {
            float tvv = Tp[j];
            if (tvv > 0.f) {
                float v = (which == 0) ? Pp[j] : tvv;
                uint32_t key = fmap(v) >> 20;
                atomicAdd(&cnt[key], 1u); atomicAdd(&fsm[key], v);
            }
        }
    }
    __syncthreads();
    {
        uint32_t ms = 0; float mf = 0.f;
        #pragma unroll
        for (int i = 0; i < 16; i++) { ms += cnt[t * 16 + i]; mf += fsm[t * 16 + i]; }
        sc[t] = ms; sfl[t] = mf;
        __syncthreads();
        for (int off = 1; off < 256; off <<= 1) {
            uint32_t a = (t >= off) ? sc[t - off] : 0u;
            float af = (t >= off) ? sfl[t - off] : 0.f;
            __syncthreads();
            sc[t] += a; sfl[t] += af;
            __syncthreads();
        }
        uint32_t incl = sc[t], excl = incl - ms;
        float fx = sfl[t] - mf;
        if (kr >= excl && kr < incl) {
            uint32_t c = excl, bin = 0, nk = 0; float f = fx;
            for (int i = 0; i < 16; i++) {
                uint32_t hv = cnt[t * 16 + i];
                if (kr < c + hv) { bin = t * 16 + i; nk = kr - c; break; }
                c += hv; f += fsm[t * 16 + i];
            }
            r_bin = bin; r_k = nk; r_f = f;
        }
    }
    __syncthreads();
    const uint32_t sel0 = r_bin;
    kr = r_k;
    if (t == 0) s_facc = r_f;
    __syncthreads();

    // ---- stage 1: mid 11 bits within sel0 ----
    for (int i = t; i < NBA; i += 256) { cnt[i] = 0; fsm[i] = 0.f; }
    __syncthreads();
    if (fast) {
        for (uint32_t j = t; j < Ctot; j += 256) {
            float v = dense[j];
            uint32_t u = fmap(v);
            if ((u >> 20) == sel0) {
                uint32_t key = (u >> 9) & (NBA - 1u);
                atomicAdd(&cnt[key], 1u); atomicAdd(&fsm[key], v);
            }
        }
    } else {
        for (int j = t; j < NPX; j += 256) {
            float tvv = Tp[j];
            if (tvv > 0.f) {
                float v = (which == 0) ? Pp[j] : tvv;
                uint32_t u = fmap(v);
                if ((u >> 20) == sel0) {
                    uint32_t key = (u >> 9) & (NBA - 1u);
                    atomicAdd(&cnt[key], 1u); atomicAdd(&fsm[key], v);
                }
            }
        }
    }
    __syncthreads();
    {
        uint32_t ms = 0; float mf = 0.f;
        #pragma unroll
        for (int i = 0; i < 8; i++) { ms += cnt[t * 8 + i]; mf += fsm[t * 8 + i]; }
        sc[t] = ms; sfl[t] = mf;
        __syncthreads();
        for (int off = 1; off < 256; off <<= 1) {
            uint32_t a = (t >= off) ? sc[t - off] : 0u;
            float af = (t >= off) ? sfl[t - off] : 0.f;
            __syncthreads();
            sc[t] += a; sfl[t] += af;
            __syncthreads();
        }
        uint32_t incl = sc[t], excl = incl - ms;
        float fx = sfl[t] - mf;
        if (kr >= excl && kr < incl) {
            uint32_t c = excl, bin = 0, nk = 0; float f = fx;
            for (int i = 0; i < 8; i++) {
                uint32_t hv = cnt[t * 8 + i];
                if (kr < c + hv) { bin = t * 8 + i; nk = kr - c; break; }
                c += hv; f += fsm[t * 8 + i];
            }
            r_bin = bin; r_k = nk; r_f = f;
        }
    }
    __syncthreads();
    const uint32_t pfx23 = (sel0 << 11) | r_bin;
    kr = r_k;
    if (t == 0) s_facc += r_f;
    __syncthreads();

    // ---- stage 2: low 9 bits ----
    for (int i = t; i < 512; i += 256) { cnt[i] = 0; fsm[i] = 0.f; }
    __syncthreads();
    if (fast) {
        for (uint32_t j = t; j < Ctot; j += 256) {
            float v = dense[j];
            uint32_t u = fmap(v);
            if ((u >> 9) == pfx23) {
                uint32_t key = u & 511u;
                atomicAdd(&cnt[key], 1u); atomicAdd(&fsm[key], v);
            }
        }
    } else {
        for (int j = t; j < NPX; j += 256) {
            float tvv = Tp[j];
            if (tvv > 0.f) {
                float v = (which == 0) ? Pp[j] : tvv;
                uint32_t u = fmap(v);
                if ((u >> 9) == pfx23) {
                    uint32_t key = u & 511u;
                    atomicAdd(&cnt[key], 1u); atomicAdd(&fsm[key], v);
                }
            }
        }
    }
    __syncthreads();
    {
        uint32_t ms = 0; float mf = 0.f;
        #pragma unroll
        for (int i = 0; i < 2; i++) { ms += cnt[t * 2 + i]; mf += fsm[t * 2 + i]; }
        sc[t] = ms; sfl[t] = mf;
        __syncthreads();
        for (int off = 1; off < 256; off <<= 1) {
            uint32_t a = (t >= off) ? sc[t - off] : 0u;
            float af = (t >= off) ? sfl[t - off] : 0.f;
            __syncthreads();
            sc[t] += a; sfl[t] += af;
            __syncthreads();
        }
        uint32_t incl = sc[t], excl = incl - ms;
        float fx = sfl[t] - mf;
        if (kr >= excl && kr < incl) {
            uint32_t c = excl, bin = 0, nk = 0, e = 0; float f = fx;
            for (int i = 0; i < 2; i++) {
                uint32_t hv = cnt[t * 2 + i];
                if (kr < c + hv) { bin = t * 2 + i; nk = kr - c; e = hv; break; }
                c += hv; f += fsm[t * 2 + i];
            }
            uint32_t u = (pfx23 << 9) | bin;
            ((float*)(ws + SH_OFF))[which * B + b] = funmap(u);
            ws[K_OFF + which * B + b] = nk;      // k3
            ws[EQ_OFF + which * B + b] = e;
            float* sb = ((float*)(ws + SB_OFF)) + which * B + b;
            float below = s_facc + f;
            *sb = fast ? (*sb + below) : below;
        }
    }
}

// ---------------- fused loss (params recomputed per block; was param_kernel) ----------------
__global__ void __launch_bounds__(256) loss_kernel(const float* __restrict__ pred,
                                                   const float* __restrict__ targ,
                                                   uint32_t* __restrict__ ws) {
    const int wid = (blockIdx.x << 2) + (threadIdx.x >> 6);
    const int b = wid / (H / RPW);
    const int s0 = (wid - b * (H / RPW)) * RPW;
    const int l = threadIdx.x & 63;
    const int col = l << 3;
    const float* Pp = pred + (size_t)b * NPX;
    const float* Tp = targ + (size_t)b * NPX;

    // ---- recompute per-sample params (identical float sequence to old param_kernel) ----
    const uint32_t n = ws[N_OFF + b];
    const uint32_t k0 = (n - 1u) >> 1;
    float med[2], rsv[2];
    uint32_t nab[2];
    #pragma unroll
    for (int w = 0; w < 2; w++) {
        float m = ((const float*)(ws + SH_OFF))[w * B + b];
        uint32_t k3 = ws[K_OFF + w * B + b];
        uint32_t e = ws[EQ_OFF + w * B + b];
        float SBv = ((const float*)(ws + SB_OFF))[w * B + b];
        float ST = ((const float*)(ws + TSUM_OFF))[w * B + b];
        uint32_t CB = k0 - k3;
        uint32_t na = n - CB - e;
        float Sab = ST - SBv - (float)e * m;
        float absdev = (Sab - (float)na * m) + ((float)CB * m - SBv);
        float scale = absdev / (float)n;
        med[w] = m; nab[w] = na;
        rsv[w] = 1.f / scale;
    }
    const uint32_t c2u = nab[1];
    if (threadIdx.x == 0) ws[C2_OFF + b] = c2u;   // same value from every block: benign
    uint32_t mi = (uint32_t)NPX - c2u + (uint32_t)TRIM_IDX;
    if (mi > (uint32_t)(NPX - 1)) mi = NPX - 1;
    const float sp = med[0], st = med[1], rp = rsv[0], rt = rsv[1];
    float thr;
    {
        float p = Pp[mi], t = Tp[mi];
        float pn_ = (p - sp) * rp, tn_ = (t - st) * rt;
        thr = (tn_ > 0.f) ? fabsf(pn_ - tn_) : 0.f;
    }

    const bool g1 = s0 >= 1, g2 = s0 >= 2, g4 = s0 >= 4, g8 = s0 >= 8;
    float rT[2][8], rPN[2][8];
    {
        const int roA = (g1 ? (s0 - 1) : s0) * W + col;
        const int roB = (g2 ? (s0 - 2) : s0) * W + col;
        float4 a0 = *(const float4*)(Tp + roA), a1 = *(const float4*)(Tp + roA + 4);
        float4 b0 = *(const float4*)(Pp + roA), b1 = *(const float4*)(Pp + roA + 4);
        float4 c0 = *(const float4*)(Tp + roB), c1 = *(const float4*)(Tp + roB + 4);
        float4 d0 = *(const float4*)(Pp + roB), d1 = *(const float4*)(Pp + roB + 4);
        float ta[8] = {a0.x,a0.y,a0.z,a0.w,a1.x,a1.y,a1.z,a1.w};
        float pa[8] = {b0.x,b0.y,b0.z,b0.w,b1.x,b1.y,b1.z,b1.w};
        float tc[8] = {c0.x,c0.y,c0.z,c0.w,c1.x,c1.y,c1.z,c1.w};
        float pc[8] = {d0.x,d0.y,d0.z,d0.w,d1.x,d1.y,d1.z,d1.w};
        #pragma unroll
        for (int k = 0; k < 8; k++) {
            rT[1][k] = ta[k]; rPN[1][k] = (pa[k] - sp) * rp;
            rT[0][k] = tc[k]; rPN[0][k] = (pc[k] - sp) * rp;
        }
    }

    float tl = 0.f, gl0 = 0.f, gl1 = 0.f, gl2 = 0.f, gl3 = 0.f;
    uint32_t mc = 0;

    #pragma unroll
    for (int it = 0; it < RPW; ++it) {
        const int ro = (s0 + it) * W + col;
        const int cur = it & 1, prv = cur ^ 1;
        float4 a0 = *(const float4*)(Tp + ro), a1 = *(const float4*)(Tp + ro + 4);
        float4 b0 = *(const float4*)(Pp + ro), b1 = *(const float4*)(Pp + ro + 4);
        float t[8] = {a0.x,a0.y,a0.z,a0.w,a1.x,a1.y,a1.z,a1.w};
        float p[8] = {b0.x,b0.y,b0.z,b0.w,b1.x,b1.y,b1.z,b1.w};
        float t4a = 0.f, t4b = 0.f, p4a = 0.f, p4b = 0.f, t8a = 0.f, p8a = 0.f;
        if (it == 0) {
            const int ro4 = g4 ? ro - 4 * W : ro;
            t4a = Tp[ro4]; t4b = Tp[ro4 + 4]; p4a = Pp[ro4]; p4b = Pp[ro4 + 4];
            const int ro8 = g8 ? ro - 8 * W : ro;
            t8a = Tp[ro8]; p8a = Pp[ro8];
        }
        if (it == 4) {
            const int ro4 = ro - 4 * W;
            t4a = Tp[ro4]; t4b = Tp[ro4 + 4]; p4a = Pp[ro4]; p4b = Pp[ro4 + 4];
        }
        float pn[8]; bool m[8];
        #pragma unroll
        for (int k = 0; k < 8; k++) { pn[k] = (p[k] - sp) * rp; m[k] = t[k] > st; }

        #pragma unroll
        for (int k = 0; k < 8; k++) {
            if (m[k]) {
                float tn = (t[k] - st) * rt;
                float r = fabsf(pn[k] - tn);
                if (r <= thr) tl += r;
            }
        }
        float t7p = __shfl_up(t[7], 1), pn7p = __shfl_up(pn[7], 1);
        if (l > 0 && m[0] && t7p > st) gl0 += fabsf(pn[0] - pn7p);
        #pragma unroll
        for (int k = 1; k < 8; k++) if (m[k] && m[k - 1]) gl0 += fabsf(pn[k] - pn[k - 1]);
        if (it > 0 || g1) {
            #pragma unroll
            for (int k = 0; k < 8; k++)
                if (m[k] && rT[prv][k] > st) gl0 += fabsf(pn[k] - rPN[prv][k]);
        }
        if ((it & 1) == 0) {
            float t6p = __shfl_up(t[6], 1), pn6p = __shfl_up(pn[6], 1);
            mc += (uint32_t)m[0] + m[2] + m[4] + m[6];
            if (l > 0 && m[0] && t6p > st) gl1 += fabsf(pn[0] - pn6p);
            if (m[2] && m[0]) gl1 += fabsf(pn[2] - pn[0]);
            if (m[4] && m[2]) gl1 += fabsf(pn[4] - pn[2]);
            if (m[6] && m[4]) gl1 += fabsf(pn[6] - pn[4]);
            if (it >= 2 || g2) {
                if (m[0] && rT[cur][0] > st) gl1 += fabsf(pn[0] - rPN[cur][0]);
                if (m[2] && rT[cur][2] > st) gl1 += fabsf(pn[2] - rPN[cur][2]);
                if (m[4] && rT[cur][4] > st) gl1 += fabsf(pn[4] - rPN[cur][4]);
                if (m[6] && rT[cur][6] > st) gl1 += fabsf(pn[6] - rPN[cur][6]);
            }
            if ((it & 3) == 0) {
                float t4p = __shfl_up(t[4], 1), pn4p = __shfl_up(pn[4], 1);
                mc += ((uint32_t)m[0] + m[4]) << 11;
                if (l > 0 && m[0] && t4p > st) gl2 += fabsf(pn[0] - pn4p);
                if (m[4] && m[0]) gl2 += fabsf(pn[4] - pn[0]);
                if (it == 4 || g4) {
                    if (m[0] && t4a > st) gl2 += fabsf(pn[0] - (p4a - sp) * rp);
                    if (m[4] && t4b > st) gl2 += fabsf(pn[4] - (p4b - sp) * rp);
                }
                if (it == 0) {
                    float t0p = __shfl_up(t[0], 1), pn0p = __shfl_up(pn[0], 1);
                    mc += ((uint32_t)m[0]) << 22;
                    if (l > 0 && m[0] && t0p > st) gl3 += fabsf(pn[0] - pn0p);
                    if (g8 && m[0] && t8a > st) gl3 += fabsf(pn[0] - (p8a - sp) * rp);
                }
            }
        }
        #pragma unroll
        for (int k = 0; k < 8; k++) { rT[cur][k] = t[k]; rPN[cur][k] = pn[k]; }
    }

    for (int off = 32; off; off >>= 1) {
        tl  += __shfl_down(tl, off, 64);
        gl0 += __shfl_down(gl0, off, 64);
        gl1 += __shfl_down(gl1, off, 64);
        gl2 += __shfl_down(gl2, off, 64);
        gl3 += __shfl_down(gl3, off, 64);
        mc  += __shfl_down(mc, off, 64);
    }
    if (l == 0) {
        float* gs = (float*)(ws + GS_OFF);
        atomicAdd(((float*)(ws + TS_OFF)) + b, tl);
        atomicAdd(gs + b, gl0);
        atomicAdd(gs + B + b, gl1);
        atomicAdd(gs + 2 * B + b, gl2);
        atomicAdd(gs + 3 * B + b, gl3);
        atomicAdd(ws + MS_OFF + b, mc & 0x7FFu);
        atomicAdd(ws + MS_OFF + B + b, (mc >> 11) & 0x7FFu);
        atomicAdd(ws + MS_OFF + 2 * B + b, mc >> 22);
    }
}

// ---------------- finalize ----------------
__global__ void finalize_kernel(const uint32_t* __restrict__ ws, float* __restrict__ out) {
    const int b = threadIdx.x;
    float v = 0.f;
    if (b < B) {
        float c2 = (float)ws[C2_OFF + b];
        const float* tsum = (const float*)(ws + TS_OFF);
        const float* gsum = (const float*)(ws + GS_OFF);
        float tm = (c2 > 0.f) ? tsum[b] / (2.f * c2) : 0.f;
        float g = (c2 > 0.f) ? gsum[b] / c2 : 0.f;
        for (int z = 0; z < 3; z++) {
            float ms = (float)ws[MS_OFF + z * B + b];
            g += (ms > 0.f) ? gsum[(1 + z) * B + b] / ms : 0.f;
        }
        v = tm + 0.5f * g;
    }
    for (int off = 32; off; off >>= 1) v += __shfl_down(v, off, 64);
    if (b == 0) out[0] = v * (1.f / 64.f);
}

extern "C" void kernel_launch(void* const* d_in, const int* in_sizes, int n_in,
                              void* d_out, int out_size, void* d_ws, size_t ws_size,
                              hipStream_t stream) {
    const float* pred = (const float*)d_in[0];
    const float* targ = (const float*)d_in[1];
    float* out = (float*)d_out;
    uint32_t* ws = (uint32_t*)d_ws;

    long avail = (long)(ws_size / 4) - (long)FIX_U32;
    int capw = 0;
    if (avail > 0) {
        long c = avail / (2L * B * NSLOT);
        capw = (int)(c < CAPW ? c : CAPW);
    }

    sample_kernel<<<dim3(B), 1024, 0, stream>>>(pred, targ, ws);
    collect_kernel<<<dim3(16, B), 256, 0, stream>>>(pred, targ, ws, capw);
    small3_kernel<<<dim3(B, 2), 256, 0, stream>>>(pred, targ, ws, capw);
    loss_kernel<<<dim3(B * (H / RPW) / 4), 256, 0, stream>>>(pred, targ, ws);
    finalize_kernel<<<1, 64, 0, stream>>>(ws, out);
}